// Round 10
// baseline (583.810 us; speedup 1.0000x reference)
//
#include <hip/hip_runtime.h>
#include <math.h>

#define BB 2
#define CC 512
#define HEADS 2
#define DH 256
#define NWIN 64
#define LTOT 4096
#define TP 3
#define LP 3
#define SCALE 0.0625f

typedef short bf16x8 __attribute__((ext_vector_type(8)));
typedef float f32x4 __attribute__((ext_vector_type(4)));

__device__ __forceinline__ int refl8(int v) {
  v = v < 0 ? -v : v;
  return v >= 8 ? 14 - v : v;
}

__device__ __forceinline__ unsigned int bf16rne(float x) {
  unsigned int u = __float_as_uint(x);
  return (u + 0x7fffu + ((u >> 16) & 1u)) >> 16;
}

__device__ __forceinline__ float bf2f(unsigned short u) {
  return __uint_as_float(((unsigned int)u) << 16);
}

// Both 1x1 convs in one launch. Y[b,o,p] = sum_c W[o,c] X[b,c,p] + bias[o]
__global__ __launch_bounds__(256) void conv_both_kernel(
    const float* __restrict__ X1, const float* __restrict__ W1,
    const float* __restrict__ b1, float* __restrict__ Y1,
    const float* __restrict__ X2, const float* __restrict__ W2,
    const float* __restrict__ b2, float* __restrict__ Y2) {
  int bidx = blockIdx.x;
  const float *X, *Wm, *bias;
  float* Y;
  int Cout;
  if (bidx < BB * (1536 / 4)) {
    X = X1; Wm = W1; bias = b1; Y = Y1; Cout = 1536;
  } else {
    bidx -= BB * (1536 / 4);
    X = X2; Wm = W2; bias = b2; Y = Y2; Cout = 1024;
  }
  int blocksPerB = Cout >> 2;
  int b = bidx / blocksPerB;
  int ob = bidx - b * blocksPerB;
  int o = ob * 4 + (threadIdx.x >> 6);
  int p = threadIdx.x & 63;
  const float* xb = X + (size_t)b * CC * 64;
  const float* wr = Wm + (size_t)o * CC;
  float acc = 0.f;
#pragma unroll 8
  for (int c = 0; c < CC; ++c) acc += wr[c] * xb[c * 64 + p];
  Y[((size_t)b * Cout + o) * 64 + p] = acc + bias[o];
}

// One block per (b, win, head). Local window attention.
// Emits qgb (B,h,L,d) row-major bf16 AND qgT (B,h,d,L) dim-major bf16.
__global__ __launch_bounds__(256) void local_attn_kernel(
    const float* __restrict__ qkvx, const float* __restrict__ qkz,
    const float* __restrict__ pbeta, unsigned short* __restrict__ qgb,
    unsigned short* __restrict__ qgT) {
  __shared__ float kbuf[64 * 132];  // reused: K phases [dd][tok], AV phase [tok][dim]
  __shared__ float att[64 * 65];
  __shared__ float red[4 * 64];
  int bid = blockIdx.x;
  int b = bid >> 7;
  int win = (bid & 127) >> 1;
  int head = bid & 1;
  int tid = threadIdx.x;
  int t = tid & 63;
  int w4 = tid >> 6;
  int wi = win >> 3, wj = win & 7;
  int ry = refl8(wi + (t >> 3) - TP);
  int rx = refl8(wj + (t & 7) - LP);
  int pix = ry * 8 + rx;
  float beta = log1pf(__expf(pbeta[0])) + 1e-6f;

  const float* qxb = qkvx + (size_t)(b * 1536 + head * DH) * 64;
  const float* kxb = qkvx + (size_t)(b * 1536 + 512 + head * DH) * 64;
  const float* vxb = qkvx + (size_t)(b * 1536 + 1024 + head * DH) * 64;
  const float* qzb = qkz + (size_t)(b * 1024 + head * DH) * 64;
  const float* kzb = qkz + (size_t)(b * 1024 + 512 + head * DH) * 64;

  float dots[16];
#pragma unroll
  for (int s = 0; s < 16; ++s) dots[s] = 0.f;
#pragma unroll
  for (int hf = 0; hf < 2; ++hf) {
    __syncthreads();
    for (int i = 0; i < 32; ++i) {
      int dd = i * 4 + w4;
      kbuf[dd * 64 + t] = kxb[(hf * 128 + dd) * 64 + pix];
    }
    __syncthreads();
    for (int dd = 0; dd < 128; ++dd) {
      float qv = qxb[(hf * 128 + dd) * 64 + pix];
#pragma unroll
      for (int s = 0; s < 16; ++s)
        dots[s] += qv * kbuf[dd * 64 + w4 * 16 + s];
    }
  }
#pragma unroll
  for (int s = 0; s < 16; ++s) att[t * 65 + w4 * 16 + s] = dots[s];
#pragma unroll
  for (int s = 0; s < 16; ++s) dots[s] = 0.f;
#pragma unroll
  for (int hf = 0; hf < 2; ++hf) {
    __syncthreads();
    for (int i = 0; i < 32; ++i) {
      int dd = i * 4 + w4;
      kbuf[dd * 64 + t] = kzb[(hf * 128 + dd) * 64 + pix];
    }
    __syncthreads();
    for (int dd = 0; dd < 128; ++dd) {
      float qv = qzb[(hf * 128 + dd) * 64 + pix];
#pragma unroll
      for (int s = 0; s < 16; ++s)
        dots[s] += qv * kbuf[dd * 64 + w4 * 16 + s];
    }
  }
  float vals[16];
  __syncthreads();
#pragma unroll
  for (int s = 0; s < 16; ++s)
    vals[s] = SCALE * (att[t * 65 + w4 * 16 + s] + beta * dots[s]);
  float mymax = -1e30f;
#pragma unroll
  for (int s = 0; s < 16; ++s) mymax = fmaxf(mymax, vals[s]);
  red[w4 * 64 + t] = mymax;
  __syncthreads();
  float m = fmaxf(fmaxf(red[t], red[64 + t]), fmaxf(red[128 + t], red[192 + t]));
  float mysum = 0.f;
#pragma unroll
  for (int s = 0; s < 16; ++s) {
    float e = __expf(vals[s] - m);
    vals[s] = e;
    mysum += e;
  }
  __syncthreads();
  red[w4 * 64 + t] = mysum;
  __syncthreads();
  float den = red[t] + red[64 + t] + red[128 + t] + red[192 + t];
  float rr = 1.f / den;
#pragma unroll
  for (int s = 0; s < 16; ++s) att[t * 65 + w4 * 16 + s] = vals[s] * rr;

  float acc[64];
#pragma unroll
  for (int j = 0; j < 64; ++j) acc[j] = 0.f;
#pragma unroll
  for (int hf = 0; hf < 2; ++hf) {
    __syncthreads();
    for (int i = 0; i < 32; ++i) {
      int dd = i * 4 + w4;
      kbuf[t * 132 + dd] = vxb[(hf * 128 + dd) * 64 + pix];
    }
    __syncthreads();
    for (int s = 0; s < 64; ++s) {
      float av = att[t * 65 + s];
      const float4* vrow = (const float4*)&kbuf[s * 132 + w4 * 32];
#pragma unroll
      for (int j = 0; j < 8; ++j) {
        float4 vv = vrow[j];
        acc[hf * 32 + j * 4 + 0] += av * vv.x;
        acc[hf * 32 + j * 4 + 1] += av * vv.y;
        acc[hf * 32 + j * 4 + 2] += av * vv.z;
        acc[hf * 32 + j * 4 + 3] += av * vv.w;
      }
    }
  }
  int bh = b * HEADS + head;
  unsigned short* dst = qgb + ((size_t)(bh * LTOT + win * 64 + t)) * DH;
  unsigned short* dstT = qgT + (size_t)bh * DH * LTOT + (size_t)win * 64 + t;
#pragma unroll
  for (int j = 0; j < 32; ++j) {
    int d0 = w4 * 32 + j;
    unsigned short v0 = (unsigned short)bf16rne(acc[j]);
    unsigned short v1 = (unsigned short)bf16rne(acc[32 + j]);
    dst[d0] = v0;
    dst[128 + d0] = v1;
    dstT[(size_t)d0 * LTOT] = v0;
    dstT[(size_t)(128 + d0) * LTOT] = v1;
  }
}

// Global flash attention, split-K (ns=2^lg), 4 waves/block, 32 q/wave
// (two 16-q groups per wave: each K/V LDS fragment read feeds 2 MFMAs).
// Round-6 staging (reg-prefetch, 2 barriers/tile); strides 16B-aligned:
// K 512B XOR-swizzled, V/P 80B (72B is misaligned for b128 -> 3x slower, r9).
__global__ __launch_bounds__(256, 2) void gattn_mfma(
    const unsigned short* __restrict__ qgb, const unsigned short* __restrict__ qgT,
    unsigned short* __restrict__ ogp, float2* __restrict__ ml, int lg) {
  __shared__ unsigned short krow[32 * 256];        // 16 KB
  __shared__ unsigned short vt[256 * 40];          // 20 KB, [dim][key], 80 B stride
  __shared__ unsigned short plds[4 * 2 * 16 * 40]; // 10 KB, [wave][grp][q][key]
  int bid = blockIdx.x;
  int nsm1 = (1 << lg) - 1;
  int split = bid & nsm1;
  int qt = (bid >> lg) & 31;
  int bh = bid >> (lg + 5);
  int ntile = 128 >> lg;
  int kt0 = split * ntile, kt1 = kt0 + ntile;
  int tid = threadIdx.x;
  int wave = tid >> 6;
  int lane = tid & 63;
  int lrow = lane & 15;
  int g = lane >> 4;
  const unsigned short* base = qgb + (size_t)bh * LTOT * DH;
  const unsigned short* baseT = qgT + (size_t)bh * DH * LTOT;
  char* krowc = (char*)krow;
  char* vtc = (char*)vt;
  char* plc0 = (char*)plds + wave * (2 * 16 * 80);
  char* plc1 = plc0 + 16 * 80;

  int qbase = qt * 128 + wave * 32;
  int qi0 = qbase + lrow;
  int qi1 = qbase + 16 + lrow;
  bf16x8 qf0[8], qf1[8];
#pragma unroll
  for (int s = 0; s < 8; ++s) {
    qf0[s] = *(const bf16x8*)(base + (size_t)qi0 * DH + s * 32 + g * 8);
    qf1[s] = *(const bf16x8*)(base + (size_t)qi1 * DH + s * 32 + g * 8);
  }

  f32x4 acc0[16], acc1[16];
#pragma unroll
  for (int f = 0; f < 16; ++f) {
    acc0[f] = (f32x4){0.f, 0.f, 0.f, 0.f};
    acc1[f] = (f32x4){0.f, 0.f, 0.f, 0.f};
  }
  float m0 = -1e30f, l0 = 0.f, m1 = -1e30f, l1 = 0.f;

  uint4 kr0, kr1, kr2, kr3, vr0, vr1, vr2, vr3;
  int skey = tid >> 5;  // 0..7
  int sdb = tid & 31;
  int sdim = tid >> 2;  // 0..63
  int sch = tid & 3;

#define LOADT(KT)                                                               \
  {                                                                             \
    const unsigned short* kb = base + (size_t)(KT) * 32 * DH;                   \
    kr0 = *(const uint4*)(kb + (skey + 0) * DH + sdb * 8);                      \
    kr1 = *(const uint4*)(kb + (skey + 8) * DH + sdb * 8);                      \
    kr2 = *(const uint4*)(kb + (skey + 16) * DH + sdb * 8);                     \
    kr3 = *(const uint4*)(kb + (skey + 24) * DH + sdb * 8);                     \
    const unsigned short* vb = baseT + (size_t)(KT) * 32 + sch * 8;             \
    vr0 = *(const uint4*)(vb + (size_t)(sdim + 0) * LTOT);                      \
    vr1 = *(const uint4*)(vb + (size_t)(sdim + 64) * LTOT);                     \
    vr2 = *(const uint4*)(vb + (size_t)(sdim + 128) * LTOT);                    \
    vr3 = *(const uint4*)(vb + (size_t)(sdim + 192) * LTOT);                    \
  }

  LOADT(kt0);
  for (int kt = kt0; kt < kt1; ++kt) {
    __syncthreads();  // all waves done reading LDS of previous tile
    // ---- write staged regs -> LDS ----
    *(uint4*)(krowc + (skey + 0) * 512 + ((sdb * 16) ^ (((skey + 0) & 7) << 4))) = kr0;
    *(uint4*)(krowc + (skey + 8) * 512 + ((sdb * 16) ^ (((skey + 8) & 7) << 4))) = kr1;
    *(uint4*)(krowc + (skey + 16) * 512 + ((sdb * 16) ^ (((skey + 16) & 7) << 4))) = kr2;
    *(uint4*)(krowc + (skey + 24) * 512 + ((sdb * 16) ^ (((skey + 24) & 7) << 4))) = kr3;
    *(uint4*)(vtc + (sdim + 0) * 80 + sch * 16) = vr0;
    *(uint4*)(vtc + (sdim + 64) * 80 + sch * 16) = vr1;
    *(uint4*)(vtc + (sdim + 128) * 80 + sch * 16) = vr2;
    *(uint4*)(vtc + (sdim + 192) * 80 + sch * 16) = vr3;
    // ---- prefetch next tile into regs ----
    if (kt + 1 < kt1) LOADT(kt + 1);
    __syncthreads();  // staged LDS visible
    // ---- S^T = K * Q^T : 32 MFMAs from 16 K-frag reads ----
    f32x4 s00 = (f32x4){0.f, 0.f, 0.f, 0.f}, s01 = s00, s10 = s00, s11 = s00;
    int sw = (lrow & 7) << 4;
    __builtin_amdgcn_s_setprio(1);
#pragma unroll
    for (int s = 0; s < 8; ++s) {
      bf16x8 k0 = *(const bf16x8*)(krowc + lrow * 512 + ((g * 16 + 64 * s) ^ sw));
      bf16x8 k1 = *(const bf16x8*)(krowc + (16 + lrow) * 512 + ((g * 16 + 64 * s) ^ sw));
      s00 = __builtin_amdgcn_mfma_f32_16x16x32_bf16(k0, qf0[s], s00, 0, 0, 0);
      s01 = __builtin_amdgcn_mfma_f32_16x16x32_bf16(k0, qf1[s], s01, 0, 0, 0);
      s10 = __builtin_amdgcn_mfma_f32_16x16x32_bf16(k1, qf0[s], s10, 0, 0, 0);
      s11 = __builtin_amdgcn_mfma_f32_16x16x32_bf16(k1, qf1[s], s11, 0, 0, 0);
    }
    __builtin_amdgcn_s_setprio(0);
    // ---- online softmax, group 0 (s00 keys 0-15, s10 keys 16-31) ----
    {
      float tmax = -1e30f;
#pragma unroll
      for (int r = 0; r < 4; ++r) {
        tmax = fmaxf(tmax, s00[r]);
        tmax = fmaxf(tmax, s10[r]);
      }
      tmax = fmaxf(tmax, __shfl_xor(tmax, 16, 64));
      tmax = fmaxf(tmax, __shfl_xor(tmax, 32, 64));
      float sm = tmax * SCALE;
      if (__any(sm > m0 + 6.f)) {
        float mn = fmaxf(m0, sm);
        float corr = __expf(m0 - mn);
#pragma unroll
        for (int f = 0; f < 16; ++f) {
          acc0[f][0] *= corr; acc0[f][1] *= corr;
          acc0[f][2] *= corr; acc0[f][3] *= corr;
        }
        l0 *= corr;
        m0 = mn;
      }
      float p[8], psum = 0.f;
#pragma unroll
      for (int r = 0; r < 4; ++r) {
        p[r] = __expf(s00[r] * SCALE - m0);
        p[4 + r] = __expf(s10[r] * SCALE - m0);
        psum += p[r] + p[4 + r];
      }
      psum += __shfl_xor(psum, 16, 64);
      psum += __shfl_xor(psum, 32, 64);
      l0 += psum;
      uint2 pk0, pk1;
      pk0.x = bf16rne(p[0]) | (bf16rne(p[1]) << 16);
      pk0.y = bf16rne(p[2]) | (bf16rne(p[3]) << 16);
      pk1.x = bf16rne(p[4]) | (bf16rne(p[5]) << 16);
      pk1.y = bf16rne(p[6]) | (bf16rne(p[7]) << 16);
      *(uint2*)(plc0 + lrow * 80 + g * 8) = pk0;
      *(uint2*)(plc0 + lrow * 80 + 32 + g * 8) = pk1;
    }
    // ---- online softmax, group 1 (s01, s11) ----
    {
      float tmax = -1e30f;
#pragma unroll
      for (int r = 0; r < 4; ++r) {
        tmax = fmaxf(tmax, s01[r]);
        tmax = fmaxf(tmax, s11[r]);
      }
      tmax = fmaxf(tmax, __shfl_xor(tmax, 16, 64));
      tmax = fmaxf(tmax, __shfl_xor(tmax, 32, 64));
      float sm = tmax * SCALE;
      if (__any(sm > m1 + 6.f)) {
        float mn = fmaxf(m1, sm);
        float corr = __expf(m1 - mn);
#pragma unroll
        for (int f = 0; f < 16; ++f) {
          acc1[f][0] *= corr; acc1[f][1] *= corr;
          acc1[f][2] *= corr; acc1[f][3] *= corr;
        }
        l1 *= corr;
        m1 = mn;
      }
      float p[8], psum = 0.f;
#pragma unroll
      for (int r = 0; r < 4; ++r) {
        p[r] = __expf(s01[r] * SCALE - m1);
        p[4 + r] = __expf(s11[r] * SCALE - m1);
        psum += p[r] + p[4 + r];
      }
      psum += __shfl_xor(psum, 16, 64);
      psum += __shfl_xor(psum, 32, 64);
      l1 += psum;
      uint2 pk0, pk1;
      pk0.x = bf16rne(p[0]) | (bf16rne(p[1]) << 16);
      pk0.y = bf16rne(p[2]) | (bf16rne(p[3]) << 16);
      pk1.x = bf16rne(p[4]) | (bf16rne(p[5]) << 16);
      pk1.y = bf16rne(p[6]) | (bf16rne(p[7]) << 16);
      *(uint2*)(plc1 + lrow * 80 + g * 8) = pk0;
      *(uint2*)(plc1 + lrow * 80 + 32 + g * 8) = pk1;
    }
    asm volatile("s_waitcnt lgkmcnt(0)" ::: "memory");
    // ---- O^T += V^T * P : 32 MFMAs from 16 V-frag reads ----
    bf16x8 pf0 = *(const bf16x8*)(plc0 + lrow * 80 + g * 16);
    bf16x8 pf1 = *(const bf16x8*)(plc1 + lrow * 80 + g * 16);
    __builtin_amdgcn_s_setprio(1);
#pragma unroll
    for (int f = 0; f < 16; ++f) {
      int dim = f * 16 + lrow;
      bf16x8 vf = *(const bf16x8*)(vtc + dim * 80 + g * 16);
      acc0[f] = __builtin_amdgcn_mfma_f32_16x16x32_bf16(vf, pf0, acc0[f], 0, 0, 0);
      acc1[f] = __builtin_amdgcn_mfma_f32_16x16x32_bf16(vf, pf1, acc1[f], 0, 0, 0);
    }
    __builtin_amdgcn_s_setprio(0);
  }
#undef LOADT
  // ---- epilogue: unnormalized partial O (bf16) + (m,l) ----
  unsigned short* dst0 = ogp + ((size_t)(split * 4 + bh) * LTOT + qi0) * DH;
  unsigned short* dst1 = ogp + ((size_t)(split * 4 + bh) * LTOT + qi1) * DH;
#pragma unroll
  for (int f = 0; f < 16; ++f) {
    uint2 pk;
    pk.x = bf16rne(acc0[f][0]) | (bf16rne(acc0[f][1]) << 16);
    pk.y = bf16rne(acc0[f][2]) | (bf16rne(acc0[f][3]) << 16);
    *(uint2*)(dst0 + f * 16 + g * 4) = pk;
    pk.x = bf16rne(acc1[f][0]) | (bf16rne(acc1[f][1]) << 16);
    pk.y = bf16rne(acc1[f][2]) | (bf16rne(acc1[f][3]) << 16);
    *(uint2*)(dst1 + f * 16 + g * 4) = pk;
  }
  if (g == 0) {
    ml[(size_t)(split * 4 + bh) * LTOT + qi0] = make_float2(m0, l0);
    ml[(size_t)(split * 4 + bh) * LTOT + qi1] = make_float2(m1, l1);
  }
}

// Combine ns splits (weights via LDS) + overlap-add gather + crop
__global__ __launch_bounds__(256) void overlap_kernel(
    const unsigned short* __restrict__ ogp, const float2* __restrict__ ml,
    float* __restrict__ crop, int ns) {
  __shared__ float wsm[4][64];
  int r = blockIdx.x;  // 256 = B*h*64 pixels
  int dim = threadIdx.x;
  int p = r & 63;
  int head = (r >> 6) & 1;
  int b = r >> 7;
  int bh = b * 2 + head;
  int y = p >> 3, x = p & 7;
  int py = y + TP, px = x + LP;
  int i0 = max(0, py - 7), i1 = min(7, py);
  int j0 = max(0, px - 7), j1 = min(7, px);
  int ni = i1 - i0 + 1, nj = j1 - j0 + 1, nq = ni * nj;
  if (dim < nq) {
    int iw = i0 + dim / nj, jw = j0 + dim % nj;
    int tok = (py - iw) * 8 + (px - jw);
    int q = (iw * 8 + jw) * 64 + tok;
    float M = -1e30f;
    for (int s = 0; s < ns; ++s)
      M = fmaxf(M, ml[(size_t)(s * 4 + bh) * 4096 + q].x);
    float D = 0.f;
    for (int s = 0; s < ns; ++s) {
      float2 a = ml[(size_t)(s * 4 + bh) * 4096 + q];
      D += a.y * __expf(a.x - M);
    }
    float rr = 1.f / D;
    for (int s = 0; s < ns; ++s)
      wsm[s][dim] = __expf(ml[(size_t)(s * 4 + bh) * 4096 + q].x - M) * rr;
  }
  __syncthreads();
  float s = 0.f;
  int t = 0;
  for (int iw = i0; iw <= i1; ++iw)
    for (int jw = j0; jw <= j1; ++jw, ++t) {
      int tok = (py - iw) * 8 + (px - jw);
      int q = (iw * 8 + jw) * 64 + tok;
      size_t e = ((size_t)bh * 4096 + q) * 256 + dim;
      for (int sp = 0; sp < ns; ++sp)
        s += wsm[sp][t] * bf2f(ogp[(size_t)sp * 4 * LTOT * DH + e]);
    }
  float cnt = (float)nq;
  crop[((size_t)b * CC + head * DH + dim) * 64 + p] = s / (cnt + 1e-6f);
}

// out = x_feat + a * (Wproj @ crop + bproj)
__global__ __launch_bounds__(256) void final_kernel(
    const float* __restrict__ crop, const float* __restrict__ Wp,
    const float* __restrict__ bp, const float* __restrict__ x_feat,
    const float* __restrict__ pa, float* __restrict__ out) {
  int blocksPerB = CC >> 2;
  int b = blockIdx.x / blocksPerB;
  int ob = blockIdx.x - b * blocksPerB;
  int o = ob * 4 + (threadIdx.x >> 6);
  int p = threadIdx.x & 63;
  float a = 2.f / (1.f + __expf(-pa[0]));
  const float* xb = crop + (size_t)b * CC * 64;
  const float* wr = Wp + (size_t)o * CC;
  float acc = 0.f;
#pragma unroll 8
  for (int c = 0; c < CC; ++c) acc += wr[c] * xb[c * 64 + p];
  size_t oi = ((size_t)b * CC + o) * 64 + p;
  out[oi] = x_feat[oi] + a * (acc + bp[o]);
}

extern "C" void kernel_launch(void* const* d_in, const int* in_sizes, int n_in,
                              void* d_out, int out_size, void* d_ws, size_t ws_size,
                              hipStream_t stream) {
  const float* x_feat = (const float*)d_in[0];
  const float* z_feat = (const float*)d_in[1];
  const float* Wqkv = (const float*)d_in[2];
  const float* bqkv = (const float*)d_in[3];
  const float* Wqkz = (const float*)d_in[4];
  const float* bqkz = (const float*)d_in[5];
  const float* Wproj = (const float*)d_in[6];
  const float* bproj = (const float*)d_in[7];
  const float* pa = (const float*)d_in[8];
  const float* pbeta = (const float*)d_in[9];
  float* ws = (float*)d_ws;
  // ns=4 needs 52.2 MB (r5 verified available); fall back to ns=2 otherwise.
  size_t need4 = (size_t)(4521984 + 4 * (2097152 + 32768)) * sizeof(float);
  int ns = (ws_size >= need4) ? 4 : 2;
  int lg = (ns == 4) ? 2 : 1;

  float* qkvx = ws;                                        // 196608 f
  float* qkz = ws + 196608;                                // 131072 f
  unsigned short* qgb = (unsigned short*)(ws + 327680);    // 2097152 f
  unsigned short* qgT = (unsigned short*)(ws + 2424832);   // 2097152 f
  unsigned short* ogp = (unsigned short*)(ws + 4521984);   // ns*2097152 f
  float2* ml = (float2*)(ws + 4521984 + ns * 2097152);     // ns*32768 f
  float* crop = ws;                                        // alias qkvx (dead after local_attn)
  float* out = (float*)d_out;

  conv_both_kernel<<<BB * (1536 / 4) + BB * (1024 / 4), 256, 0, stream>>>(
      x_feat, Wqkv, bqkv, qkvx, z_feat, Wqkz, bqkz, qkz);
  local_attn_kernel<<<256, 256, 0, stream>>>(qkvx, qkz, pbeta, qgb, qgT);
  gattn_mfma<<<128 * ns, 256, 0, stream>>>(qgb, qgT, ogp, ml, lg);
  overlap_kernel<<<256, 256, 0, stream>>>(ogp, ml, crop, ns);
  final_kernel<<<BB * (CC / 4), 256, 0, stream>>>(crop, Wproj, bproj, x_feat, pa, out);
}

// Round 11
// 280.294 us; speedup vs baseline: 2.0829x; 2.0829x over previous
//
#include <hip/hip_runtime.h>
#include <math.h>

#define BB 2
#define CC 512
#define HEADS 2
#define DH 256
#define NWIN 64
#define LTOT 4096
#define TP 3
#define LP 3
#define SCALE 0.0625f

typedef short bf16x8 __attribute__((ext_vector_type(8)));
typedef float f32x4 __attribute__((ext_vector_type(4)));

__device__ __forceinline__ int refl8(int v) {
  v = v < 0 ? -v : v;
  return v >= 8 ? 14 - v : v;
}

__device__ __forceinline__ unsigned int bf16rne(float x) {
  unsigned int u = __float_as_uint(x);
  return (u + 0x7fffu + ((u >> 16) & 1u)) >> 16;
}

__device__ __forceinline__ float bf2f(unsigned short u) {
  return __uint_as_float(((unsigned int)u) << 16);
}

// Both 1x1 convs in one launch. Y[b,o,p] = sum_c W[o,c] X[b,c,p] + bias[o]
__global__ __launch_bounds__(256) void conv_both_kernel(
    const float* __restrict__ X1, const float* __restrict__ W1,
    const float* __restrict__ b1, float* __restrict__ Y1,
    const float* __restrict__ X2, const float* __restrict__ W2,
    const float* __restrict__ b2, float* __restrict__ Y2) {
  int bidx = blockIdx.x;
  const float *X, *Wm, *bias;
  float* Y;
  int Cout;
  if (bidx < BB * (1536 / 4)) {
    X = X1; Wm = W1; bias = b1; Y = Y1; Cout = 1536;
  } else {
    bidx -= BB * (1536 / 4);
    X = X2; Wm = W2; bias = b2; Y = Y2; Cout = 1024;
  }
  int blocksPerB = Cout >> 2;
  int b = bidx / blocksPerB;
  int ob = bidx - b * blocksPerB;
  int o = ob * 4 + (threadIdx.x >> 6);
  int p = threadIdx.x & 63;
  const float* xb = X + (size_t)b * CC * 64;
  const float* wr = Wm + (size_t)o * CC;
  float acc = 0.f;
#pragma unroll 8
  for (int c = 0; c < CC; ++c) acc += wr[c] * xb[c * 64 + p];
  Y[((size_t)b * Cout + o) * 64 + p] = acc + bias[o];
}

// One block per (b, win, head). Local window attention.
// Emits qgb (B,h,L,d) row-major bf16 AND qgT (B,h,d,L) dim-major bf16.
__global__ __launch_bounds__(256) void local_attn_kernel(
    const float* __restrict__ qkvx, const float* __restrict__ qkz,
    const float* __restrict__ pbeta, unsigned short* __restrict__ qgb,
    unsigned short* __restrict__ qgT) {
  __shared__ float kbuf[64 * 132];  // reused: K phases [dd][tok], AV phase [tok][dim]
  __shared__ float att[64 * 65];
  __shared__ float red[4 * 64];
  int bid = blockIdx.x;
  int b = bid >> 7;
  int win = (bid & 127) >> 1;
  int head = bid & 1;
  int tid = threadIdx.x;
  int t = tid & 63;
  int w4 = tid >> 6;
  int wi = win >> 3, wj = win & 7;
  int ry = refl8(wi + (t >> 3) - TP);
  int rx = refl8(wj + (t & 7) - LP);
  int pix = ry * 8 + rx;
  float beta = log1pf(__expf(pbeta[0])) + 1e-6f;

  const float* qxb = qkvx + (size_t)(b * 1536 + head * DH) * 64;
  const float* kxb = qkvx + (size_t)(b * 1536 + 512 + head * DH) * 64;
  const float* vxb = qkvx + (size_t)(b * 1536 + 1024 + head * DH) * 64;
  const float* qzb = qkz + (size_t)(b * 1024 + head * DH) * 64;
  const float* kzb = qkz + (size_t)(b * 1024 + 512 + head * DH) * 64;

  float dots[16];
#pragma unroll
  for (int s = 0; s < 16; ++s) dots[s] = 0.f;
#pragma unroll
  for (int hf = 0; hf < 2; ++hf) {
    __syncthreads();
    for (int i = 0; i < 32; ++i) {
      int dd = i * 4 + w4;
      kbuf[dd * 64 + t] = kxb[(hf * 128 + dd) * 64 + pix];
    }
    __syncthreads();
    for (int dd = 0; dd < 128; ++dd) {
      float qv = qxb[(hf * 128 + dd) * 64 + pix];
#pragma unroll
      for (int s = 0; s < 16; ++s)
        dots[s] += qv * kbuf[dd * 64 + w4 * 16 + s];
    }
  }
#pragma unroll
  for (int s = 0; s < 16; ++s) att[t * 65 + w4 * 16 + s] = dots[s];
#pragma unroll
  for (int s = 0; s < 16; ++s) dots[s] = 0.f;
#pragma unroll
  for (int hf = 0; hf < 2; ++hf) {
    __syncthreads();
    for (int i = 0; i < 32; ++i) {
      int dd = i * 4 + w4;
      kbuf[dd * 64 + t] = kzb[(hf * 128 + dd) * 64 + pix];
    }
    __syncthreads();
    for (int dd = 0; dd < 128; ++dd) {
      float qv = qzb[(hf * 128 + dd) * 64 + pix];
#pragma unroll
      for (int s = 0; s < 16; ++s)
        dots[s] += qv * kbuf[dd * 64 + w4 * 16 + s];
    }
  }
  float vals[16];
  __syncthreads();
#pragma unroll
  for (int s = 0; s < 16; ++s)
    vals[s] = SCALE * (att[t * 65 + w4 * 16 + s] + beta * dots[s]);
  float mymax = -1e30f;
#pragma unroll
  for (int s = 0; s < 16; ++s) mymax = fmaxf(mymax, vals[s]);
  red[w4 * 64 + t] = mymax;
  __syncthreads();
  float m = fmaxf(fmaxf(red[t], red[64 + t]), fmaxf(red[128 + t], red[192 + t]));
  float mysum = 0.f;
#pragma unroll
  for (int s = 0; s < 16; ++s) {
    float e = __expf(vals[s] - m);
    vals[s] = e;
    mysum += e;
  }
  __syncthreads();
  red[w4 * 64 + t] = mysum;
  __syncthreads();
  float den = red[t] + red[64 + t] + red[128 + t] + red[192 + t];
  float rr = 1.f / den;
#pragma unroll
  for (int s = 0; s < 16; ++s) att[t * 65 + w4 * 16 + s] = vals[s] * rr;

  float acc[64];
#pragma unroll
  for (int j = 0; j < 64; ++j) acc[j] = 0.f;
#pragma unroll
  for (int hf = 0; hf < 2; ++hf) {
    __syncthreads();
    for (int i = 0; i < 32; ++i) {
      int dd = i * 4 + w4;
      kbuf[t * 132 + dd] = vxb[(hf * 128 + dd) * 64 + pix];
    }
    __syncthreads();
    for (int s = 0; s < 64; ++s) {
      float av = att[t * 65 + s];
      const float4* vrow = (const float4*)&kbuf[s * 132 + w4 * 32];
#pragma unroll
      for (int j = 0; j < 8; ++j) {
        float4 vv = vrow[j];
        acc[hf * 32 + j * 4 + 0] += av * vv.x;
        acc[hf * 32 + j * 4 + 1] += av * vv.y;
        acc[hf * 32 + j * 4 + 2] += av * vv.z;
        acc[hf * 32 + j * 4 + 3] += av * vv.w;
      }
    }
  }
  int bh = b * HEADS + head;
  unsigned short* dst = qgb + ((size_t)(bh * LTOT + win * 64 + t)) * DH;
  unsigned short* dstT = qgT + (size_t)bh * DH * LTOT + (size_t)win * 64 + t;
#pragma unroll
  for (int j = 0; j < 32; ++j) {
    int d0 = w4 * 32 + j;
    unsigned short v0 = (unsigned short)bf16rne(acc[j]);
    unsigned short v1 = (unsigned short)bf16rne(acc[32 + j]);
    dst[d0] = v0;
    dst[128 + d0] = v1;
    dstT[(size_t)d0 * LTOT] = v0;
    dstT[(size_t)(128 + d0) * LTOT] = v1;
  }
}

// Global flash attention, split-K 2-way, 4 waves/block, 16 q/wave.
// Round-6 proven config: reg-staged prefetch, 2 barriers/tile, K 512B
// XOR-swizzled, V/P stride 80 B (16B-aligned; 72B misaligns b128 -> 3x slow).
__global__ __launch_bounds__(256, 2) void gattn_mfma(
    const unsigned short* __restrict__ qgb, const unsigned short* __restrict__ qgT,
    unsigned short* __restrict__ ogp, float2* __restrict__ ml) {
  __shared__ unsigned short krow[32 * 256];  // 16 KB, XOR-swizzled rows
  __shared__ unsigned short vt[256 * 40];    // 20 KB, [dim][key], 80 B stride
  __shared__ unsigned short plds[4 * 16 * 40];
  int bid = blockIdx.x;
  int split = bid & 1;
  int qt = (bid >> 1) & 63;
  int bh = bid >> 7;
  int kt0 = split * 64, kt1 = kt0 + 64;
  int qtile = qt * 64;
  int tid = threadIdx.x;
  int wave = tid >> 6;
  int lane = tid & 63;
  int lrow = lane & 15;
  int g = lane >> 4;
  const unsigned short* base = qgb + (size_t)bh * LTOT * DH;
  const unsigned short* baseT = qgT + (size_t)bh * DH * LTOT;
  char* krowc = (char*)krow;
  char* vtc = (char*)vt;
  char* plc = (char*)plds + wave * 16 * 80;

  int qi = qtile + wave * 16 + lrow;
  bf16x8 qf[8];
#pragma unroll
  for (int s = 0; s < 8; ++s)
    qf[s] = *(const bf16x8*)(base + (size_t)qi * DH + s * 32 + g * 8);

  f32x4 acc[16];
#pragma unroll
  for (int f = 0; f < 16; ++f) acc[f] = (f32x4){0.f, 0.f, 0.f, 0.f};
  float m = -1e30f, l = 0.f;

  uint4 kr0, kr1, kr2, kr3, vr0, vr1, vr2, vr3;
  int skey = tid >> 5;  // 0..7
  int sdb = tid & 31;
  int sdim = tid >> 2;  // 0..63
  int sch = tid & 3;

#define LOADT(KT)                                                               \
  {                                                                             \
    const unsigned short* kb = base + (size_t)(KT) * 32 * DH;                   \
    kr0 = *(const uint4*)(kb + (skey + 0) * DH + sdb * 8);                      \
    kr1 = *(const uint4*)(kb + (skey + 8) * DH + sdb * 8);                      \
    kr2 = *(const uint4*)(kb + (skey + 16) * DH + sdb * 8);                     \
    kr3 = *(const uint4*)(kb + (skey + 24) * DH + sdb * 8);                     \
    const unsigned short* vb = baseT + (size_t)(KT) * 32 + sch * 8;             \
    vr0 = *(const uint4*)(vb + (size_t)(sdim + 0) * LTOT);                      \
    vr1 = *(const uint4*)(vb + (size_t)(sdim + 64) * LTOT);                     \
    vr2 = *(const uint4*)(vb + (size_t)(sdim + 128) * LTOT);                    \
    vr3 = *(const uint4*)(vb + (size_t)(sdim + 192) * LTOT);                    \
  }

  LOADT(kt0);
  for (int kt = kt0; kt < kt1; ++kt) {
    __syncthreads();  // all waves done reading LDS of previous tile
    // ---- write staged regs -> LDS ----
    *(uint4*)(krowc + (skey + 0) * 512 + ((sdb * 16) ^ (((skey + 0) & 7) << 4))) = kr0;
    *(uint4*)(krowc + (skey + 8) * 512 + ((sdb * 16) ^ (((skey + 8) & 7) << 4))) = kr1;
    *(uint4*)(krowc + (skey + 16) * 512 + ((sdb * 16) ^ (((skey + 16) & 7) << 4))) = kr2;
    *(uint4*)(krowc + (skey + 24) * 512 + ((sdb * 16) ^ (((skey + 24) & 7) << 4))) = kr3;
    *(uint4*)(vtc + (sdim + 0) * 80 + sch * 16) = vr0;
    *(uint4*)(vtc + (sdim + 64) * 80 + sch * 16) = vr1;
    *(uint4*)(vtc + (sdim + 128) * 80 + sch * 16) = vr2;
    *(uint4*)(vtc + (sdim + 192) * 80 + sch * 16) = vr3;
    // ---- prefetch next tile into regs (latency hides under compute) ----
    if (kt + 1 < kt1) LOADT(kt + 1);
    __syncthreads();  // staged LDS visible
    // ---- S^T = K * Q^T (16 MFMAs, 4 independent chains) ----
    f32x4 s0a = (f32x4){0.f, 0.f, 0.f, 0.f}, s0b = s0a, s1a = s0a, s1b = s0a;
    int key0 = lrow, key1 = 16 + lrow;
    int sw = (lrow & 7) << 4;
    __builtin_amdgcn_s_setprio(1);
#pragma unroll
    for (int s = 0; s < 4; ++s) {
      bf16x8 k0 = *(const bf16x8*)(krowc + key0 * 512 + ((g * 16 + 64 * s) ^ sw));
      s0a = __builtin_amdgcn_mfma_f32_16x16x32_bf16(k0, qf[s], s0a, 0, 0, 0);
      bf16x8 k0b = *(const bf16x8*)(krowc + key0 * 512 + ((g * 16 + 64 * (s + 4)) ^ sw));
      s0b = __builtin_amdgcn_mfma_f32_16x16x32_bf16(k0b, qf[s + 4], s0b, 0, 0, 0);
      bf16x8 k1 = *(const bf16x8*)(krowc + key1 * 512 + ((g * 16 + 64 * s) ^ sw));
      s1a = __builtin_amdgcn_mfma_f32_16x16x32_bf16(k1, qf[s], s1a, 0, 0, 0);
      bf16x8 k1b = *(const bf16x8*)(krowc + key1 * 512 + ((g * 16 + 64 * (s + 4)) ^ sw));
      s1b = __builtin_amdgcn_mfma_f32_16x16x32_bf16(k1b, qf[s + 4], s1b, 0, 0, 0);
    }
    __builtin_amdgcn_s_setprio(0);
    f32x4 st0 = s0a + s0b;
    f32x4 st1 = s1a + s1b;
    // ---- online softmax with deferred rescale (thr=6) ----
    float tmax = -1e30f;
#pragma unroll
    for (int r = 0; r < 4; ++r) {
      tmax = fmaxf(tmax, st0[r]);
      tmax = fmaxf(tmax, st1[r]);
    }
    tmax = fmaxf(tmax, __shfl_xor(tmax, 16, 64));
    tmax = fmaxf(tmax, __shfl_xor(tmax, 32, 64));
    float sm = tmax * SCALE;
    if (__any(sm > m + 6.f)) {
      float mn = fmaxf(m, sm);
      float corr = __expf(m - mn);
#pragma unroll
      for (int f = 0; f < 16; ++f) {
        acc[f][0] *= corr; acc[f][1] *= corr;
        acc[f][2] *= corr; acc[f][3] *= corr;
      }
      l *= corr;
      m = mn;
    }
    float p[8];
    float psum = 0.f;
#pragma unroll
    for (int r = 0; r < 4; ++r) {
      p[r] = __expf(st0[r] * SCALE - m);
      p[4 + r] = __expf(st1[r] * SCALE - m);
      psum += p[r] + p[4 + r];
    }
    psum += __shfl_xor(psum, 16, 64);
    psum += __shfl_xor(psum, 32, 64);
    l += psum;
    // ---- write P^T (bf16) to per-wave LDS: plds[query][key] ----
    {
      uint2 pk0, pk1;
      pk0.x = bf16rne(p[0]) | (bf16rne(p[1]) << 16);
      pk0.y = bf16rne(p[2]) | (bf16rne(p[3]) << 16);
      pk1.x = bf16rne(p[4]) | (bf16rne(p[5]) << 16);
      pk1.y = bf16rne(p[6]) | (bf16rne(p[7]) << 16);
      *(uint2*)(plc + lrow * 80 + g * 8) = pk0;
      *(uint2*)(plc + lrow * 80 + 32 + g * 8) = pk1;
    }
    asm volatile("s_waitcnt lgkmcnt(0)" ::: "memory");
    // ---- O^T += V^T * P (16 MFMAs) ----
    bf16x8 pf = *(const bf16x8*)(plc + lrow * 80 + g * 16);
    __builtin_amdgcn_s_setprio(1);
#pragma unroll
    for (int f = 0; f < 16; ++f) {
      int dim = f * 16 + lrow;
      bf16x8 vf = *(const bf16x8*)(vtc + dim * 80 + g * 16);
      acc[f] = __builtin_amdgcn_mfma_f32_16x16x32_bf16(vf, pf, acc[f], 0, 0, 0);
    }
    __builtin_amdgcn_s_setprio(0);
  }
#undef LOADT
  // ---- epilogue: store unnormalized partial O as bf16 + (m,l) ----
  unsigned short* dstp = ogp + ((size_t)(split * 4 + bh) * LTOT + qi) * DH;
#pragma unroll
  for (int f = 0; f < 16; ++f) {
    uint2 pk;
    pk.x = bf16rne(acc[f][0]) | (bf16rne(acc[f][1]) << 16);
    pk.y = bf16rne(acc[f][2]) | (bf16rne(acc[f][3]) << 16);
    *(uint2*)(dstp + f * 16 + g * 4) = pk;
  }
  if (g == 0) ml[(size_t)(split * 4 + bh) * LTOT + qi] = make_float2(m, l);
}

// Combine splits (weights via LDS) + overlap-add gather + crop -> crop (B,C,64)
__global__ __launch_bounds__(256) void overlap_kernel(
    const unsigned short* __restrict__ ogp, const float2* __restrict__ ml,
    float* __restrict__ crop) {
  __shared__ float w0s[64], w1s[64];
  int r = blockIdx.x;  // 256 = B*h*64 pixels
  int dim = threadIdx.x;
  int p = r & 63;
  int head = (r >> 6) & 1;
  int b = r >> 7;
  int bh = b * 2 + head;
  int y = p >> 3, x = p & 7;
  int py = y + TP, px = x + LP;
  int i0 = max(0, py - 7), i1 = min(7, py);
  int j0 = max(0, px - 7), j1 = min(7, px);
  int ni = i1 - i0 + 1, nj = j1 - j0 + 1, nq = ni * nj;
  if (dim < nq) {
    int iw = i0 + dim / nj, jw = j0 + dim % nj;
    int tok = (py - iw) * 8 + (px - jw);
    int q = (iw * 8 + jw) * 64 + tok;
    float2 a = ml[(size_t)bh * 4096 + q];
    float2 c = ml[(size_t)(4 + bh) * 4096 + q];
    float M = fmaxf(a.x, c.x);
    float e0 = __expf(a.x - M), e1 = __expf(c.x - M);
    float rr = 1.f / (a.y * e0 + c.y * e1);
    w0s[dim] = e0 * rr;
    w1s[dim] = e1 * rr;
  }
  __syncthreads();
  float s = 0.f;
  int t = 0;
  for (int iw = i0; iw <= i1; ++iw)
    for (int jw = j0; jw <= j1; ++jw, ++t) {
      int tok = (py - iw) * 8 + (px - jw);
      int q = (iw * 8 + jw) * 64 + tok;
      size_t e = ((size_t)bh * 4096 + q) * 256 + dim;
      s += w0s[t] * bf2f(ogp[e]) + w1s[t] * bf2f(ogp[(size_t)4 * LTOT * DH + e]);
    }
  float cnt = (float)nq;
  crop[((size_t)b * CC + head * DH + dim) * 64 + p] = s / (cnt + 1e-6f);
}

// out = x_feat + a * (Wproj @ crop + bproj)
__global__ __launch_bounds__(256) void final_kernel(
    const float* __restrict__ crop, const float* __restrict__ Wp,
    const float* __restrict__ bp, const float* __restrict__ x_feat,
    const float* __restrict__ pa, float* __restrict__ out) {
  int blocksPerB = CC >> 2;
  int b = blockIdx.x / blocksPerB;
  int ob = blockIdx.x - b * blocksPerB;
  int o = ob * 4 + (threadIdx.x >> 6);
  int p = threadIdx.x & 63;
  float a = 2.f / (1.f + __expf(-pa[0]));
  const float* xb = crop + (size_t)b * CC * 64;
  const float* wr = Wp + (size_t)o * CC;
  float acc = 0.f;
#pragma unroll 8
  for (int c = 0; c < CC; ++c) acc += wr[c] * xb[c * 64 + p];
  size_t oi = ((size_t)b * CC + o) * 64 + p;
  out[oi] = x_feat[oi] + a * (acc + bp[o]);
}

extern "C" void kernel_launch(void* const* d_in, const int* in_sizes, int n_in,
                              void* d_out, int out_size, void* d_ws, size_t ws_size,
                              hipStream_t stream) {
  const float* x_feat = (const float*)d_in[0];
  const float* z_feat = (const float*)d_in[1];
  const float* Wqkv = (const float*)d_in[2];
  const float* bqkv = (const float*)d_in[3];
  const float* Wqkz = (const float*)d_in[4];
  const float* bqkz = (const float*)d_in[5];
  const float* Wproj = (const float*)d_in[6];
  const float* bproj = (const float*)d_in[7];
  const float* pa = (const float*)d_in[8];
  const float* pbeta = (const float*)d_in[9];
  float* ws = (float*)d_ws;
  float* qkvx = ws;                                        // 196608 f
  float* qkz = ws + 196608;                                // 131072 f
  unsigned short* qgb = (unsigned short*)(ws + 327680);    // 2097152 f
  unsigned short* qgT = (unsigned short*)(ws + 2424832);   // 2097152 f
  unsigned short* ogp = (unsigned short*)(ws + 4521984);   // 4194304 f (2 splits)
  float2* ml = (float2*)(ws + 8716288);                    // 65536 f
  float* crop = ws;                                        // alias qkvx (dead after local_attn)
  float* out = (float*)d_out;

  conv_both_kernel<<<BB * (1536 / 4) + BB * (1024 / 4), 256, 0, stream>>>(
      x_feat, Wqkv, bqkv, qkvx, z_feat, Wqkz, bqkz, qkz);
  local_attn_kernel<<<256, 256, 0, stream>>>(qkvx, qkz, pbeta, qgb, qgT);
  gattn_mfma<<<512, 256, 0, stream>>>(qgb, qgT, ogp, ml);
  overlap_kernel<<<256, 256, 0, stream>>>(ogp, ml, crop);
  final_kernel<<<BB * (CC / 4), 256, 0, stream>>>(crop, Wproj, bproj, x_feat, pa, out);
}

// Round 12
// 271.478 us; speedup vs baseline: 2.1505x; 1.0325x over previous
//
#include <hip/hip_runtime.h>
#include <math.h>

#define BB 2
#define CC 512
#define HEADS 2
#define DH 256
#define NWIN 64
#define LTOT 4096
#define TP 3
#define LP 3
#define SCALE 0.0625f

typedef short bf16x8 __attribute__((ext_vector_type(8)));
typedef float f32x4 __attribute__((ext_vector_type(4)));

__device__ __forceinline__ int refl8(int v) {
  v = v < 0 ? -v : v;
  return v >= 8 ? 14 - v : v;
}

__device__ __forceinline__ unsigned int bf16rne(float x) {
  unsigned int u = __float_as_uint(x);
  return (u + 0x7fffu + ((u >> 16) & 1u)) >> 16;
}

__device__ __forceinline__ float bf2f(unsigned short u) {
  return __uint_as_float(((unsigned int)u) << 16);
}

// Both 1x1 convs in one launch. Y[b,o,p] = sum_c W[o,c] X[b,c,p] + bias[o]
__global__ __launch_bounds__(256) void conv_both_kernel(
    const float* __restrict__ X1, const float* __restrict__ W1,
    const float* __restrict__ b1, float* __restrict__ Y1,
    const float* __restrict__ X2, const float* __restrict__ W2,
    const float* __restrict__ b2, float* __restrict__ Y2) {
  int bidx = blockIdx.x;
  const float *X, *Wm, *bias;
  float* Y;
  int Cout;
  if (bidx < BB * (1536 / 4)) {
    X = X1; Wm = W1; bias = b1; Y = Y1; Cout = 1536;
  } else {
    bidx -= BB * (1536 / 4);
    X = X2; Wm = W2; bias = b2; Y = Y2; Cout = 1024;
  }
  int blocksPerB = Cout >> 2;
  int b = bidx / blocksPerB;
  int ob = bidx - b * blocksPerB;
  int o = ob * 4 + (threadIdx.x >> 6);
  int p = threadIdx.x & 63;
  const float* xb = X + (size_t)b * CC * 64;
  const float* wr = Wm + (size_t)o * CC;
  float acc = 0.f;
#pragma unroll 8
  for (int c = 0; c < CC; ++c) acc += wr[c] * xb[c * 64 + p];
  Y[((size_t)b * Cout + o) * 64 + p] = acc + bias[o];
}

// One block per (b, win, head). Local window attention.
// Emits qgb (B,h,L,d) row-major bf16 AND qgT (B,h,d,L) dim-major bf16.
// r12: explicit register-prefetch on all global gather loads (1 blk/CU ->
// no TLP; ILP via 16-deep load bursts is the only latency hiding available).
__global__ __launch_bounds__(256) void local_attn_kernel(
    const float* __restrict__ qkvx, const float* __restrict__ qkz,
    const float* __restrict__ pbeta, unsigned short* __restrict__ qgb,
    unsigned short* __restrict__ qgT) {
  __shared__ float kbuf[64 * 132];  // reused: K phases [dd][tok], AV phase [tok][dim]
  __shared__ float att[64 * 65];
  __shared__ float red[4 * 64];
  int bid = blockIdx.x;
  int b = bid >> 7;
  int win = (bid & 127) >> 1;
  int head = bid & 1;
  int tid = threadIdx.x;
  int t = tid & 63;
  int w4 = tid >> 6;
  int wi = win >> 3, wj = win & 7;
  int ry = refl8(wi + (t >> 3) - TP);
  int rx = refl8(wj + (t & 7) - LP);
  int pix = ry * 8 + rx;
  float beta = log1pf(__expf(pbeta[0])) + 1e-6f;

  const float* qxb = qkvx + (size_t)(b * 1536 + head * DH) * 64;
  const float* kxb = qkvx + (size_t)(b * 1536 + 512 + head * DH) * 64;
  const float* vxb = qkvx + (size_t)(b * 1536 + 1024 + head * DH) * 64;
  const float* qzb = qkz + (size_t)(b * 1024 + head * DH) * 64;
  const float* kzb = qkz + (size_t)(b * 1024 + 512 + head * DH) * 64;

  float dots[16];
#pragma unroll
  for (int s = 0; s < 16; ++s) dots[s] = 0.f;
  // ---- lx = qx . kx ----
#pragma unroll
  for (int hf = 0; hf < 2; ++hf) {
    __syncthreads();
    {
      float kv[32];
#pragma unroll
      for (int i = 0; i < 32; ++i)
        kv[i] = kxb[(hf * 128 + i * 4 + w4) * 64 + pix];
#pragma unroll
      for (int i = 0; i < 32; ++i)
        kbuf[(i * 4 + w4) * 64 + t] = kv[i];
    }
    __syncthreads();
    float qv[2][16];
#pragma unroll
    for (int i = 0; i < 16; ++i) qv[0][i] = qxb[(hf * 128 + i) * 64 + pix];
#pragma unroll
    for (int dc = 0; dc < 128; dc += 16) {
      int cur = (dc >> 4) & 1;
      if (dc + 16 < 128) {
#pragma unroll
        for (int i = 0; i < 16; ++i)
          qv[cur ^ 1][i] = qxb[(hf * 128 + dc + 16 + i) * 64 + pix];
      }
#pragma unroll
      for (int i = 0; i < 16; ++i) {
        float q = qv[cur][i];
#pragma unroll
        for (int s = 0; s < 16; ++s)
          dots[s] += q * kbuf[(dc + i) * 64 + w4 * 16 + s];
      }
    }
  }
#pragma unroll
  for (int s = 0; s < 16; ++s) att[t * 65 + w4 * 16 + s] = dots[s];
  // ---- lz = qz . kz ----
#pragma unroll
  for (int s = 0; s < 16; ++s) dots[s] = 0.f;
#pragma unroll
  for (int hf = 0; hf < 2; ++hf) {
    __syncthreads();
    {
      float kv[32];
#pragma unroll
      for (int i = 0; i < 32; ++i)
        kv[i] = kzb[(hf * 128 + i * 4 + w4) * 64 + pix];
#pragma unroll
      for (int i = 0; i < 32; ++i)
        kbuf[(i * 4 + w4) * 64 + t] = kv[i];
    }
    __syncthreads();
    float qv[2][16];
#pragma unroll
    for (int i = 0; i < 16; ++i) qv[0][i] = qzb[(hf * 128 + i) * 64 + pix];
#pragma unroll
    for (int dc = 0; dc < 128; dc += 16) {
      int cur = (dc >> 4) & 1;
      if (dc + 16 < 128) {
#pragma unroll
        for (int i = 0; i < 16; ++i)
          qv[cur ^ 1][i] = qzb[(hf * 128 + dc + 16 + i) * 64 + pix];
      }
#pragma unroll
      for (int i = 0; i < 16; ++i) {
        float q = qv[cur][i];
#pragma unroll
        for (int s = 0; s < 16; ++s)
          dots[s] += q * kbuf[(dc + i) * 64 + w4 * 16 + s];
      }
    }
  }
  // combine logits in regs, block-parallel softmax
  float vals[16];
  __syncthreads();
#pragma unroll
  for (int s = 0; s < 16; ++s)
    vals[s] = SCALE * (att[t * 65 + w4 * 16 + s] + beta * dots[s]);
  float mymax = -1e30f;
#pragma unroll
  for (int s = 0; s < 16; ++s) mymax = fmaxf(mymax, vals[s]);
  red[w4 * 64 + t] = mymax;
  __syncthreads();
  float m = fmaxf(fmaxf(red[t], red[64 + t]), fmaxf(red[128 + t], red[192 + t]));
  float mysum = 0.f;
#pragma unroll
  for (int s = 0; s < 16; ++s) {
    float e = __expf(vals[s] - m);
    vals[s] = e;
    mysum += e;
  }
  __syncthreads();
  red[w4 * 64 + t] = mysum;
  __syncthreads();
  float den = red[t] + red[64 + t] + red[128 + t] + red[192 + t];
  float rr = 1.f / den;
#pragma unroll
  for (int s = 0; s < 16; ++s) att[t * 65 + w4 * 16 + s] = vals[s] * rr;

  float acc[64];
#pragma unroll
  for (int j = 0; j < 64; ++j) acc[j] = 0.f;
#pragma unroll
  for (int hf = 0; hf < 2; ++hf) {
    __syncthreads();
    {
      float vv[32];
#pragma unroll
      for (int i = 0; i < 32; ++i)
        vv[i] = vxb[(hf * 128 + i * 4 + w4) * 64 + pix];
#pragma unroll
      for (int i = 0; i < 32; ++i)
        kbuf[t * 132 + i * 4 + w4] = vv[i];
    }
    __syncthreads();
    for (int s = 0; s < 64; ++s) {
      float av = att[t * 65 + s];
      const float4* vrow = (const float4*)&kbuf[s * 132 + w4 * 32];
#pragma unroll
      for (int j = 0; j < 8; ++j) {
        float4 vv = vrow[j];
        acc[hf * 32 + j * 4 + 0] += av * vv.x;
        acc[hf * 32 + j * 4 + 1] += av * vv.y;
        acc[hf * 32 + j * 4 + 2] += av * vv.z;
        acc[hf * 32 + j * 4 + 3] += av * vv.w;
      }
    }
  }
  int bh = b * HEADS + head;
  unsigned short* dst = qgb + ((size_t)(bh * LTOT + win * 64 + t)) * DH;
  unsigned short* dstT = qgT + (size_t)bh * DH * LTOT + (size_t)win * 64 + t;
#pragma unroll
  for (int j = 0; j < 32; ++j) {
    int d0 = w4 * 32 + j;
    unsigned short v0 = (unsigned short)bf16rne(acc[j]);
    unsigned short v1 = (unsigned short)bf16rne(acc[32 + j]);
    dst[d0] = v0;
    dst[128 + d0] = v1;
    dstT[(size_t)d0 * LTOT] = v0;
    dstT[(size_t)(128 + d0) * LTOT] = v1;
  }
}

// Global flash attention, split-K 2-way, 4 waves/block, 16 q/wave.
// Round-6 proven config: reg-staged prefetch, 2 barriers/tile, K 512B
// XOR-swizzled, V/P stride 80 B (16B-aligned; 72B misaligns b128 -> 3x slow).
__global__ __launch_bounds__(256, 2) void gattn_mfma(
    const unsigned short* __restrict__ qgb, const unsigned short* __restrict__ qgT,
    unsigned short* __restrict__ ogp, float2* __restrict__ ml) {
  __shared__ unsigned short krow[32 * 256];  // 16 KB, XOR-swizzled rows
  __shared__ unsigned short vt[256 * 40];    // 20 KB, [dim][key], 80 B stride
  __shared__ unsigned short plds[4 * 16 * 40];
  int bid = blockIdx.x;
  int split = bid & 1;
  int qt = (bid >> 1) & 63;
  int bh = bid >> 7;
  int kt0 = split * 64, kt1 = kt0 + 64;
  int qtile = qt * 64;
  int tid = threadIdx.x;
  int wave = tid >> 6;
  int lane = tid & 63;
  int lrow = lane & 15;
  int g = lane >> 4;
  const unsigned short* base = qgb + (size_t)bh * LTOT * DH;
  const unsigned short* baseT = qgT + (size_t)bh * DH * LTOT;
  char* krowc = (char*)krow;
  char* vtc = (char*)vt;
  char* plc = (char*)plds + wave * 16 * 80;

  int qi = qtile + wave * 16 + lrow;
  bf16x8 qf[8];
#pragma unroll
  for (int s = 0; s < 8; ++s)
    qf[s] = *(const bf16x8*)(base + (size_t)qi * DH + s * 32 + g * 8);

  f32x4 acc[16];
#pragma unroll
  for (int f = 0; f < 16; ++f) acc[f] = (f32x4){0.f, 0.f, 0.f, 0.f};
  float m = -1e30f, l = 0.f;

  uint4 kr0, kr1, kr2, kr3, vr0, vr1, vr2, vr3;
  int skey = tid >> 5;  // 0..7
  int sdb = tid & 31;
  int sdim = tid >> 2;  // 0..63
  int sch = tid & 3;

#define LOADT(KT)                                                               \
  {                                                                             \
    const unsigned short* kb = base + (size_t)(KT) * 32 * DH;                   \
    kr0 = *(const uint4*)(kb + (skey + 0) * DH + sdb * 8);                      \
    kr1 = *(const uint4*)(kb + (skey + 8) * DH + sdb * 8);                      \
    kr2 = *(const uint4*)(kb + (skey + 16) * DH + sdb * 8);                     \
    kr3 = *(const uint4*)(kb + (skey + 24) * DH + sdb * 8);                     \
    const unsigned short* vb = baseT + (size_t)(KT) * 32 + sch * 8;             \
    vr0 = *(const uint4*)(vb + (size_t)(sdim + 0) * LTOT);                      \
    vr1 = *(const uint4*)(vb + (size_t)(sdim + 64) * LTOT);                     \
    vr2 = *(const uint4*)(vb + (size_t)(sdim + 128) * LTOT);                    \
    vr3 = *(const uint4*)(vb + (size_t)(sdim + 192) * LTOT);                    \
  }

  LOADT(kt0);
  for (int kt = kt0; kt < kt1; ++kt) {
    __syncthreads();  // all waves done reading LDS of previous tile
    // ---- write staged regs -> LDS ----
    *(uint4*)(krowc + (skey + 0) * 512 + ((sdb * 16) ^ (((skey + 0) & 7) << 4))) = kr0;
    *(uint4*)(krowc + (skey + 8) * 512 + ((sdb * 16) ^ (((skey + 8) & 7) << 4))) = kr1;
    *(uint4*)(krowc + (skey + 16) * 512 + ((sdb * 16) ^ (((skey + 16) & 7) << 4))) = kr2;
    *(uint4*)(krowc + (skey + 24) * 512 + ((sdb * 16) ^ (((skey + 24) & 7) << 4))) = kr3;
    *(uint4*)(vtc + (sdim + 0) * 80 + sch * 16) = vr0;
    *(uint4*)(vtc + (sdim + 64) * 80 + sch * 16) = vr1;
    *(uint4*)(vtc + (sdim + 128) * 80 + sch * 16) = vr2;
    *(uint4*)(vtc + (sdim + 192) * 80 + sch * 16) = vr3;
    // ---- prefetch next tile into regs (latency hides under compute) ----
    if (kt + 1 < kt1) LOADT(kt + 1);
    __syncthreads();  // staged LDS visible
    // ---- S^T = K * Q^T (16 MFMAs, 4 independent chains) ----
    f32x4 s0a = (f32x4){0.f, 0.f, 0.f, 0.f}, s0b = s0a, s1a = s0a, s1b = s0a;
    int key0 = lrow, key1 = 16 + lrow;
    int sw = (lrow & 7) << 4;
    __builtin_amdgcn_s_setprio(1);
#pragma unroll
    for (int s = 0; s < 4; ++s) {
      bf16x8 k0 = *(const bf16x8*)(krowc + key0 * 512 + ((g * 16 + 64 * s) ^ sw));
      s0a = __builtin_amdgcn_mfma_f32_16x16x32_bf16(k0, qf[s], s0a, 0, 0, 0);
      bf16x8 k0b = *(const bf16x8*)(krowc + key0 * 512 + ((g * 16 + 64 * (s + 4)) ^ sw));
      s0b = __builtin_amdgcn_mfma_f32_16x16x32_bf16(k0b, qf[s + 4], s0b, 0, 0, 0);
      bf16x8 k1 = *(const bf16x8*)(krowc + key1 * 512 + ((g * 16 + 64 * s) ^ sw));
      s1a = __builtin_amdgcn_mfma_f32_16x16x32_bf16(k1, qf[s], s1a, 0, 0, 0);
      bf16x8 k1b = *(const bf16x8*)(krowc + key1 * 512 + ((g * 16 + 64 * (s + 4)) ^ sw));
      s1b = __builtin_amdgcn_mfma_f32_16x16x32_bf16(k1b, qf[s + 4], s1b, 0, 0, 0);
    }
    __builtin_amdgcn_s_setprio(0);
    f32x4 st0 = s0a + s0b;
    f32x4 st1 = s1a + s1b;
    // ---- online softmax with deferred rescale (thr=6) ----
    float tmax = -1e30f;
#pragma unroll
    for (int r = 0; r < 4; ++r) {
      tmax = fmaxf(tmax, st0[r]);
      tmax = fmaxf(tmax, st1[r]);
    }
    tmax = fmaxf(tmax, __shfl_xor(tmax, 16, 64));
    tmax = fmaxf(tmax, __shfl_xor(tmax, 32, 64));
    float sm = tmax * SCALE;
    if (__any(sm > m + 6.f)) {
      float mn = fmaxf(m, sm);
      float corr = __expf(m - mn);
#pragma unroll
      for (int f = 0; f < 16; ++f) {
        acc[f][0] *= corr; acc[f][1] *= corr;
        acc[f][2] *= corr; acc[f][3] *= corr;
      }
      l *= corr;
      m = mn;
    }
    float p[8];
    float psum = 0.f;
#pragma unroll
    for (int r = 0; r < 4; ++r) {
      p[r] = __expf(st0[r] * SCALE - m);
      p[4 + r] = __expf(st1[r] * SCALE - m);
      psum += p[r] + p[4 + r];
    }
    psum += __shfl_xor(psum, 16, 64);
    psum += __shfl_xor(psum, 32, 64);
    l += psum;
    // ---- write P^T (bf16) to per-wave LDS: plds[query][key] ----
    {
      uint2 pk0, pk1;
      pk0.x = bf16rne(p[0]) | (bf16rne(p[1]) << 16);
      pk0.y = bf16rne(p[2]) | (bf16rne(p[3]) << 16);
      pk1.x = bf16rne(p[4]) | (bf16rne(p[5]) << 16);
      pk1.y = bf16rne(p[6]) | (bf16rne(p[7]) << 16);
      *(uint2*)(plc + lrow * 80 + g * 8) = pk0;
      *(uint2*)(plc + lrow * 80 + 32 + g * 8) = pk1;
    }
    asm volatile("s_waitcnt lgkmcnt(0)" ::: "memory");
    // ---- O^T += V^T * P (16 MFMAs) ----
    bf16x8 pf = *(const bf16x8*)(plc + lrow * 80 + g * 16);
    __builtin_amdgcn_s_setprio(1);
#pragma unroll
    for (int f = 0; f < 16; ++f) {
      int dim = f * 16 + lrow;
      bf16x8 vf = *(const bf16x8*)(vtc + dim * 80 + g * 16);
      acc[f] = __builtin_amdgcn_mfma_f32_16x16x32_bf16(vf, pf, acc[f], 0, 0, 0);
    }
    __builtin_amdgcn_s_setprio(0);
  }
#undef LOADT
  // ---- epilogue: store unnormalized partial O as bf16 + (m,l) ----
  unsigned short* dstp = ogp + ((size_t)(split * 4 + bh) * LTOT + qi) * DH;
#pragma unroll
  for (int f = 0; f < 16; ++f) {
    uint2 pk;
    pk.x = bf16rne(acc[f][0]) | (bf16rne(acc[f][1]) << 16);
    pk.y = bf16rne(acc[f][2]) | (bf16rne(acc[f][3]) << 16);
    *(uint2*)(dstp + f * 16 + g * 4) = pk;
  }
  if (g == 0) ml[(size_t)(split * 4 + bh) * LTOT + qi] = make_float2(m, l);
}

// Combine splits (weights via LDS) + overlap-add gather + crop -> crop (B,C,64)
__global__ __launch_bounds__(256) void overlap_kernel(
    const unsigned short* __restrict__ ogp, const float2* __restrict__ ml,
    float* __restrict__ crop) {
  __shared__ float w0s[64], w1s[64];
  int r = blockIdx.x;  // 256 = B*h*64 pixels
  int dim = threadIdx.x;
  int p = r & 63;
  int head = (r >> 6) & 1;
  int b = r >> 7;
  int bh = b * 2 + head;
  int y = p >> 3, x = p & 7;
  int py = y + TP, px = x + LP;
  int i0 = max(0, py - 7), i1 = min(7, py);
  int j0 = max(0, px - 7), j1 = min(7, px);
  int ni = i1 - i0 + 1, nj = j1 - j0 + 1, nq = ni * nj;
  if (dim < nq) {
    int iw = i0 + dim / nj, jw = j0 + dim % nj;
    int tok = (py - iw) * 8 + (px - jw);
    int q = (iw * 8 + jw) * 64 + tok;
    float2 a = ml[(size_t)bh * 4096 + q];
    float2 c = ml[(size_t)(4 + bh) * 4096 + q];
    float M = fmaxf(a.x, c.x);
    float e0 = __expf(a.x - M), e1 = __expf(c.x - M);
    float rr = 1.f / (a.y * e0 + c.y * e1);
    w0s[dim] = e0 * rr;
    w1s[dim] = e1 * rr;
  }
  __syncthreads();
  float s = 0.f;
  int t = 0;
  for (int iw = i0; iw <= i1; ++iw)
    for (int jw = j0; jw <= j1; ++jw, ++t) {
      int tok = (py - iw) * 8 + (px - jw);
      int q = (iw * 8 + jw) * 64 + tok;
      size_t e = ((size_t)bh * 4096 + q) * 256 + dim;
      s += w0s[t] * bf2f(ogp[e]) + w1s[t] * bf2f(ogp[(size_t)4 * LTOT * DH + e]);
    }
  float cnt = (float)nq;
  crop[((size_t)b * CC + head * DH + dim) * 64 + p] = s / (cnt + 1e-6f);
}

// out = x_feat + a * (Wproj @ crop + bproj)
__global__ __launch_bounds__(256) void final_kernel(
    const float* __restrict__ crop, const float* __restrict__ Wp,
    const float* __restrict__ bp, const float* __restrict__ x_feat,
    const float* __restrict__ pa, float* __restrict__ out) {
  int blocksPerB = CC >> 2;
  int b = blockIdx.x / blocksPerB;
  int ob = blockIdx.x - b * blocksPerB;
  int o = ob * 4 + (threadIdx.x >> 6);
  int p = threadIdx.x & 63;
  float a = 2.f / (1.f + __expf(-pa[0]));
  const float* xb = crop + (size_t)b * CC * 64;
  const float* wr = Wp + (size_t)o * CC;
  float acc = 0.f;
#pragma unroll 8
  for (int c = 0; c < CC; ++c) acc += wr[c] * xb[c * 64 + p];
  size_t oi = ((size_t)b * CC + o) * 64 + p;
  out[oi] = x_feat[oi] + a * (acc + bp[o]);
}

extern "C" void kernel_launch(void* const* d_in, const int* in_sizes, int n_in,
                              void* d_out, int out_size, void* d_ws, size_t ws_size,
                              hipStream_t stream) {
  const float* x_feat = (const float*)d_in[0];
  const float* z_feat = (const float*)d_in[1];
  const float* Wqkv = (const float*)d_in[2];
  const float* bqkv = (const float*)d_in[3];
  const float* Wqkz = (const float*)d_in[4];
  const float* bqkz = (const float*)d_in[5];
  const float* Wproj = (const float*)d_in[6];
  const float* bproj = (const float*)d_in[7];
  const float* pa = (const float*)d_in[8];
  const float* pbeta = (const float*)d_in[9];
  float* ws = (float*)d_ws;
  float* qkvx = ws;                                        // 196608 f
  float* qkz = ws + 196608;                                // 131072 f
  unsigned short* qgb = (unsigned short*)(ws + 327680);    // 2097152 f
  unsigned short* qgT = (unsigned short*)(ws + 2424832);   // 2097152 f
  unsigned short* ogp = (unsigned short*)(ws + 4521984);   // 4194304 f (2 splits)
  float2* ml = (float2*)(ws + 8716288);                    // 65536 f
  float* crop = ws;                                        // alias qkvx (dead after local_attn)
  float* out = (float*)d_out;

  conv_both_kernel<<<BB * (1536 / 4) + BB * (1024 / 4), 256, 0, stream>>>(
      x_feat, Wqkv, bqkv, qkvx, z_feat, Wqkz, bqkz, qkz);
  local_attn_kernel<<<256, 256, 0, stream>>>(qkvx, qkz, pbeta, qgb, qgT);
  gattn_mfma<<<512, 256, 0, stream>>>(qgb, qgT, ogp, ml);
  overlap_kernel<<<256, 256, 0, stream>>>(ogp, ml, crop);
  final_kernel<<<BB * (CC / 4), 256, 0, stream>>>(crop, Wproj, bproj, x_feat, pa, out);
}

// Round 13
// 228.273 us; speedup vs baseline: 2.5575x; 1.1893x over previous
//
#include <hip/hip_runtime.h>
#include <math.h>

#define BB 2
#define CC 512
#define HEADS 2
#define DH 256
#define NWIN 64
#define LTOT 4096
#define TP 3
#define LP 3
#define SCALE 0.0625f

typedef short bf16x8 __attribute__((ext_vector_type(8)));
typedef float f32x4 __attribute__((ext_vector_type(4)));

__device__ __forceinline__ int refl8(int v) {
  v = v < 0 ? -v : v;
  return v >= 8 ? 14 - v : v;
}

__device__ __forceinline__ unsigned int bf16rne(float x) {
  unsigned int u = __float_as_uint(x);
  return (u + 0x7fffu + ((u >> 16) & 1u)) >> 16;
}

__device__ __forceinline__ float bf2f(unsigned short u) {
  return __uint_as_float(((unsigned int)u) << 16);
}

// Both 1x1 convs in one launch. Y[b,o,p] = sum_c W[o,c] X[b,c,p] + bias[o]
__global__ __launch_bounds__(256) void conv_both_kernel(
    const float* __restrict__ X1, const float* __restrict__ W1,
    const float* __restrict__ b1, float* __restrict__ Y1,
    const float* __restrict__ X2, const float* __restrict__ W2,
    const float* __restrict__ b2, float* __restrict__ Y2) {
  int bidx = blockIdx.x;
  const float *X, *Wm, *bias;
  float* Y;
  int Cout;
  if (bidx < BB * (1536 / 4)) {
    X = X1; Wm = W1; bias = b1; Y = Y1; Cout = 1536;
  } else {
    bidx -= BB * (1536 / 4);
    X = X2; Wm = W2; bias = b2; Y = Y2; Cout = 1024;
  }
  int blocksPerB = Cout >> 2;
  int b = bidx / blocksPerB;
  int ob = bidx - b * blocksPerB;
  int o = ob * 4 + (threadIdx.x >> 6);
  int p = threadIdx.x & 63;
  const float* xb = X + (size_t)b * CC * 64;
  const float* wr = Wm + (size_t)o * CC;
  float acc = 0.f;
#pragma unroll 8
  for (int c = 0; c < CC; ++c) acc += wr[c] * xb[c * 64 + p];
  Y[((size_t)b * Cout + o) * 64 + p] = acc + bias[o];
}

// One block per (b, win, head). Local window attention via MFMA.
// All fragment layouts copied 1:1 from the verified gattn_mfma kernel:
// K/Q rows 512 B XOR-swizzled, V^T/P 80 B stride, S^T = mfma(K,Q).
__global__ __launch_bounds__(256, 1) void local_attn_kernel(
    const float* __restrict__ qkvx, const float* __restrict__ qkz,
    const float* __restrict__ pbeta, unsigned short* __restrict__ qgb,
    unsigned short* __restrict__ qgT) {
  __shared__ unsigned short qk[64 * 256];           // 32 KB: Q staging, then K tiles
  __shared__ unsigned short vt[256 * 40];           // 20 KB: V^T tile, 80 B stride
  __shared__ unsigned short plds[4 * 16 * 2 * 40];  // 10 KB: per-wave P, both tiles
  __shared__ int pixlds[64];
  int bid = blockIdx.x;
  int b = bid >> 7;
  int win = (bid & 127) >> 1;
  int head = bid & 1;
  int tid = threadIdx.x;
  int wave = tid >> 6;
  int lane = tid & 63;
  int lrow = lane & 15;
  int g = lane >> 4;
  int wi = win >> 3, wj = win & 7;
  float beta = log1pf(__expf(pbeta[0])) + 1e-6f;

  const float* qxb = qkvx + (size_t)(b * 1536 + head * DH) * 64;
  const float* kxb = qkvx + (size_t)(b * 1536 + 512 + head * DH) * 64;
  const float* vxb = qkvx + (size_t)(b * 1536 + 1024 + head * DH) * 64;
  const float* qzb = qkz + (size_t)(b * 1024 + head * DH) * 64;
  const float* kzb = qkz + (size_t)(b * 1024 + 512 + head * DH) * 64;

  if (tid < 64) {
    int ry = refl8(wi + (tid >> 3) - TP);
    int rx = refl8(wj + (tid & 7) - LP);
    pixlds[tid] = ry * 8 + rx;
  }
  __syncthreads();
  char* qkc = (char*)qk;
  char* vtc = (char*)vt;
  char* plc = (char*)plds + wave * (16 * 2 * 80);

  // ---- stage Q row-major [64][256] bf16 (XOR-swizzled), read frags ----
  int sq = tid >> 2;   // row 0..63
  int sdg = tid & 3;   // 64-channel group
#define STAGE_Q(SRC)                                                          \
  {                                                                           \
    const float* s0 = (SRC) + pixlds[sq];                                     \
    _Pragma("unroll")                                                         \
    for (int blk = 0; blk < 4; ++blk) {                                       \
      float v[16];                                                            \
      _Pragma("unroll")                                                       \
      for (int j = 0; j < 16; ++j) v[j] = s0[(sdg * 64 + blk * 16 + j) * 64]; \
      unsigned int w[8];                                                      \
      _Pragma("unroll")                                                       \
      for (int j = 0; j < 8; ++j)                                             \
        w[j] = bf16rne(v[2 * j]) | (bf16rne(v[2 * j + 1]) << 16);             \
      int colb = sdg * 128 + blk * 32;                                        \
      *(uint4*)(qkc + sq * 512 + ((colb) ^ ((sq & 7) << 4))) =                \
          make_uint4(w[0], w[1], w[2], w[3]);                                 \
      *(uint4*)(qkc + sq * 512 + ((colb + 16) ^ ((sq & 7) << 4))) =           \
          make_uint4(w[4], w[5], w[6], w[7]);                                 \
    }                                                                         \
  }
  bf16x8 qfx[8], qfz[8];
  int qrow = wave * 16 + lrow;
  int qsw = (qrow & 7) << 4;
  STAGE_Q(qxb);
  __syncthreads();
#pragma unroll
  for (int s = 0; s < 8; ++s)
    qfx[s] = *(const bf16x8*)(qkc + qrow * 512 + ((s * 64 + g * 16) ^ qsw));
  __syncthreads();
  STAGE_Q(qzb);
  __syncthreads();
#pragma unroll
  for (int s = 0; s < 8; ++s)
    qfz[s] = *(const bf16x8*)(qkc + qrow * 512 + ((s * 64 + g * 16) ^ qsw));
  __syncthreads();

  // ---- K tiles (32 keys x 256 ch) staged into first 16 KB of qk ----
  int skey = tid >> 3;  // 0..31
  int skdg = tid & 7;   // 32-channel group
#define STAGE_K(SRC, T2)                                                      \
  {                                                                           \
    const float* s0 = (SRC) + pixlds[(T2) * 32 + skey];                       \
    _Pragma("unroll")                                                         \
    for (int blk = 0; blk < 2; ++blk) {                                       \
      float v[16];                                                            \
      _Pragma("unroll")                                                       \
      for (int j = 0; j < 16; ++j) v[j] = s0[(skdg * 32 + blk * 16 + j) * 64];\
      unsigned int w[8];                                                      \
      _Pragma("unroll")                                                       \
      for (int j = 0; j < 8; ++j)                                             \
        w[j] = bf16rne(v[2 * j]) | (bf16rne(v[2 * j + 1]) << 16);             \
      int colb = skdg * 64 + blk * 32;                                        \
      *(uint4*)(qkc + skey * 512 + ((colb) ^ ((skey & 7) << 4))) =            \
          make_uint4(w[0], w[1], w[2], w[3]);                                 \
      *(uint4*)(qkc + skey * 512 + ((colb + 16) ^ ((skey & 7) << 4))) =       \
          make_uint4(w[4], w[5], w[6], w[7]);                                 \
    }                                                                         \
  }
#define COMPUTE_S(QF, OUT0, OUT1)                                             \
  {                                                                           \
    f32x4 a0 = (f32x4){0.f, 0.f, 0.f, 0.f}, a1 = a0, b0 = a0, b1 = a0;        \
    int sw = (lrow & 7) << 4;                                                 \
    _Pragma("unroll")                                                         \
    for (int s = 0; s < 4; ++s) {                                             \
      bf16x8 k0 = *(const bf16x8*)(qkc + lrow * 512 + ((g * 16 + 64 * s) ^ sw)); \
      a0 = __builtin_amdgcn_mfma_f32_16x16x32_bf16(k0, (QF)[s], a0, 0, 0, 0); \
      bf16x8 k0b = *(const bf16x8*)(qkc + lrow * 512 + ((g * 16 + 64 * (s + 4)) ^ sw)); \
      a1 = __builtin_amdgcn_mfma_f32_16x16x32_bf16(k0b, (QF)[s + 4], a1, 0, 0, 0); \
      bf16x8 k1 = *(const bf16x8*)(qkc + (16 + lrow) * 512 + ((g * 16 + 64 * s) ^ sw)); \
      b0 = __builtin_amdgcn_mfma_f32_16x16x32_bf16(k1, (QF)[s], b0, 0, 0, 0); \
      bf16x8 k1b = *(const bf16x8*)(qkc + (16 + lrow) * 512 + ((g * 16 + 64 * (s + 4)) ^ sw)); \
      b1 = __builtin_amdgcn_mfma_f32_16x16x32_bf16(k1b, (QF)[s + 4], b1, 0, 0, 0); \
    }                                                                         \
    OUT0 = a0 + a1;                                                           \
    OUT1 = b0 + b1;                                                           \
  }
  float lgt[16];
#pragma unroll
  for (int t2 = 0; t2 < 2; ++t2) {
    STAGE_K(kxb, t2);
    __syncthreads();
    f32x4 sx0, sx1;
    COMPUTE_S(qfx, sx0, sx1);
    __syncthreads();
    STAGE_K(kzb, t2);
    __syncthreads();
    f32x4 sz0, sz1;
    COMPUTE_S(qfz, sz0, sz1);
    __syncthreads();
#pragma unroll
    for (int r = 0; r < 4; ++r) {
      lgt[t2 * 8 + r] = SCALE * (sx0[r] + beta * sz0[r]);
      lgt[t2 * 8 + 4 + r] = SCALE * (sx1[r] + beta * sz1[r]);
    }
  }
  // ---- full-row softmax: 16 regs + shfl over key-groups ----
  float mx = -1e30f;
#pragma unroll
  for (int i = 0; i < 16; ++i) mx = fmaxf(mx, lgt[i]);
  mx = fmaxf(mx, __shfl_xor(mx, 16, 64));
  mx = fmaxf(mx, __shfl_xor(mx, 32, 64));
  float p[16];
  float sum = 0.f;
#pragma unroll
  for (int i = 0; i < 16; ++i) {
    p[i] = __expf(lgt[i] - mx);
    sum += p[i];
  }
  sum += __shfl_xor(sum, 16, 64);
  sum += __shfl_xor(sum, 32, 64);
  float rr = 1.f / sum;
#pragma unroll
  for (int i = 0; i < 16; ++i) p[i] *= rr;
#pragma unroll
  for (int t2 = 0; t2 < 2; ++t2) {
    uint2 pk0, pk1;
    pk0.x = bf16rne(p[t2 * 8 + 0]) | (bf16rne(p[t2 * 8 + 1]) << 16);
    pk0.y = bf16rne(p[t2 * 8 + 2]) | (bf16rne(p[t2 * 8 + 3]) << 16);
    pk1.x = bf16rne(p[t2 * 8 + 4]) | (bf16rne(p[t2 * 8 + 5]) << 16);
    pk1.y = bf16rne(p[t2 * 8 + 6]) | (bf16rne(p[t2 * 8 + 7]) << 16);
    *(uint2*)(plc + (lrow * 2 + t2) * 80 + g * 8) = pk0;
    *(uint2*)(plc + (lrow * 2 + t2) * 80 + 32 + g * 8) = pk1;
  }
  asm volatile("s_waitcnt lgkmcnt(0)" ::: "memory");
  // ---- PV over 2 tiles, V^T staged [dim][key] stride 80 ----
  f32x4 acc[16];
#pragma unroll
  for (int f = 0; f < 16; ++f) acc[f] = (f32x4){0.f, 0.f, 0.f, 0.f};
  int svd = tid >> 2;  // dim base 0..63
  int svk = tid & 3;   // 8-key group
#pragma unroll
  for (int t2 = 0; t2 < 2; ++t2) {
    {
      int pk8[8];
#pragma unroll
      for (int j = 0; j < 8; ++j) pk8[j] = pixlds[t2 * 32 + svk * 8 + j];
#pragma unroll
      for (int r = 0; r < 4; ++r) {
        int dim = r * 64 + svd;
        const float* s0 = vxb + (size_t)dim * 64;
        float v[8];
#pragma unroll
        for (int j = 0; j < 8; ++j) v[j] = s0[pk8[j]];
        unsigned int w[4];
#pragma unroll
        for (int j = 0; j < 4; ++j)
          w[j] = bf16rne(v[2 * j]) | (bf16rne(v[2 * j + 1]) << 16);
        *(uint4*)(vtc + dim * 80 + svk * 16) = make_uint4(w[0], w[1], w[2], w[3]);
      }
    }
    __syncthreads();
    bf16x8 pf = *(const bf16x8*)(plc + (lrow * 2 + t2) * 80 + g * 16);
#pragma unroll
    for (int f = 0; f < 16; ++f) {
      int dim = f * 16 + lrow;
      bf16x8 vf = *(const bf16x8*)(vtc + dim * 80 + g * 16);
      acc[f] = __builtin_amdgcn_mfma_f32_16x16x32_bf16(vf, pf, acc[f], 0, 0, 0);
    }
    __syncthreads();
  }
  // ---- epilogue: O^T[dim][q] -> qgb row + qgT scatter ----
  int gtok = win * 64 + wave * 16 + lrow;
  int bh = b * HEADS + head;
  unsigned short* dst = qgb + ((size_t)(bh * LTOT + gtok)) * DH;
  unsigned short* dstT = qgT + (size_t)bh * DH * LTOT + gtok;
#pragma unroll
  for (int f = 0; f < 16; ++f) {
    unsigned int e0 = bf16rne(acc[f][0]), e1 = bf16rne(acc[f][1]);
    unsigned int e2 = bf16rne(acc[f][2]), e3 = bf16rne(acc[f][3]);
    uint2 pk;
    pk.x = e0 | (e1 << 16);
    pk.y = e2 | (e3 << 16);
    *(uint2*)(dst + f * 16 + g * 4) = pk;
    dstT[(size_t)(f * 16 + g * 4 + 0) * LTOT] = (unsigned short)e0;
    dstT[(size_t)(f * 16 + g * 4 + 1) * LTOT] = (unsigned short)e1;
    dstT[(size_t)(f * 16 + g * 4 + 2) * LTOT] = (unsigned short)e2;
    dstT[(size_t)(f * 16 + g * 4 + 3) * LTOT] = (unsigned short)e3;
  }
#undef STAGE_Q
#undef STAGE_K
#undef COMPUTE_S
}

// Global flash attention, split-K 2-way, 4 waves/block, 16 q/wave.
// Round-6 proven config: reg-staged prefetch, 2 barriers/tile, K 512B
// XOR-swizzled, V/P stride 80 B (16B-aligned; 72B misaligns b128 -> 3x slow).
__global__ __launch_bounds__(256, 2) void gattn_mfma(
    const unsigned short* __restrict__ qgb, const unsigned short* __restrict__ qgT,
    unsigned short* __restrict__ ogp, float2* __restrict__ ml) {
  __shared__ unsigned short krow[32 * 256];  // 16 KB, XOR-swizzled rows
  __shared__ unsigned short vt[256 * 40];    // 20 KB, [dim][key], 80 B stride
  __shared__ unsigned short plds[4 * 16 * 40];
  int bid = blockIdx.x;
  int split = bid & 1;
  int qt = (bid >> 1) & 63;
  int bh = bid >> 7;
  int kt0 = split * 64, kt1 = kt0 + 64;
  int qtile = qt * 64;
  int tid = threadIdx.x;
  int wave = tid >> 6;
  int lane = tid & 63;
  int lrow = lane & 15;
  int g = lane >> 4;
  const unsigned short* base = qgb + (size_t)bh * LTOT * DH;
  const unsigned short* baseT = qgT + (size_t)bh * DH * LTOT;
  char* krowc = (char*)krow;
  char* vtc = (char*)vt;
  char* plc = (char*)plds + wave * 16 * 80;

  int qi = qtile + wave * 16 + lrow;
  bf16x8 qf[8];
#pragma unroll
  for (int s = 0; s < 8; ++s)
    qf[s] = *(const bf16x8*)(base + (size_t)qi * DH + s * 32 + g * 8);

  f32x4 acc[16];
#pragma unroll
  for (int f = 0; f < 16; ++f) acc[f] = (f32x4){0.f, 0.f, 0.f, 0.f};
  float m = -1e30f, l = 0.f;

  uint4 kr0, kr1, kr2, kr3, vr0, vr1, vr2, vr3;
  int skey = tid >> 5;  // 0..7
  int sdb = tid & 31;
  int sdim = tid >> 2;  // 0..63
  int sch = tid & 3;

#define LOADT(KT)                                                               \
  {                                                                             \
    const unsigned short* kb = base + (size_t)(KT) * 32 * DH;                   \
    kr0 = *(const uint4*)(kb + (skey + 0) * DH + sdb * 8);                      \
    kr1 = *(const uint4*)(kb + (skey + 8) * DH + sdb * 8);                      \
    kr2 = *(const uint4*)(kb + (skey + 16) * DH + sdb * 8);                     \
    kr3 = *(const uint4*)(kb + (skey + 24) * DH + sdb * 8);                     \
    const unsigned short* vb = baseT + (size_t)(KT) * 32 + sch * 8;             \
    vr0 = *(const uint4*)(vb + (size_t)(sdim + 0) * LTOT);                      \
    vr1 = *(const uint4*)(vb + (size_t)(sdim + 64) * LTOT);                     \
    vr2 = *(const uint4*)(vb + (size_t)(sdim + 128) * LTOT);                    \
    vr3 = *(const uint4*)(vb + (size_t)(sdim + 192) * LTOT);                    \
  }

  LOADT(kt0);
  for (int kt = kt0; kt < kt1; ++kt) {
    __syncthreads();  // all waves done reading LDS of previous tile
    // ---- write staged regs -> LDS ----
    *(uint4*)(krowc + (skey + 0) * 512 + ((sdb * 16) ^ (((skey + 0) & 7) << 4))) = kr0;
    *(uint4*)(krowc + (skey + 8) * 512 + ((sdb * 16) ^ (((skey + 8) & 7) << 4))) = kr1;
    *(uint4*)(krowc + (skey + 16) * 512 + ((sdb * 16) ^ (((skey + 16) & 7) << 4))) = kr2;
    *(uint4*)(krowc + (skey + 24) * 512 + ((sdb * 16) ^ (((skey + 24) & 7) << 4))) = kr3;
    *(uint4*)(vtc + (sdim + 0) * 80 + sch * 16) = vr0;
    *(uint4*)(vtc + (sdim + 64) * 80 + sch * 16) = vr1;
    *(uint4*)(vtc + (sdim + 128) * 80 + sch * 16) = vr2;
    *(uint4*)(vtc + (sdim + 192) * 80 + sch * 16) = vr3;
    // ---- prefetch next tile into regs (latency hides under compute) ----
    if (kt + 1 < kt1) LOADT(kt + 1);
    __syncthreads();  // staged LDS visible
    // ---- S^T = K * Q^T (16 MFMAs, 4 independent chains) ----
    f32x4 s0a = (f32x4){0.f, 0.f, 0.f, 0.f}, s0b = s0a, s1a = s0a, s1b = s0a;
    int key0 = lrow, key1 = 16 + lrow;
    int sw = (lrow & 7) << 4;
    __builtin_amdgcn_s_setprio(1);
#pragma unroll
    for (int s = 0; s < 4; ++s) {
      bf16x8 k0 = *(const bf16x8*)(krowc + key0 * 512 + ((g * 16 + 64 * s) ^ sw));
      s0a = __builtin_amdgcn_mfma_f32_16x16x32_bf16(k0, qf[s], s0a, 0, 0, 0);
      bf16x8 k0b = *(const bf16x8*)(krowc + key0 * 512 + ((g * 16 + 64 * (s + 4)) ^ sw));
      s0b = __builtin_amdgcn_mfma_f32_16x16x32_bf16(k0b, qf[s + 4], s0b, 0, 0, 0);
      bf16x8 k1 = *(const bf16x8*)(krowc + key1 * 512 + ((g * 16 + 64 * s) ^ sw));
      s1a = __builtin_amdgcn_mfma_f32_16x16x32_bf16(k1, qf[s], s1a, 0, 0, 0);
      bf16x8 k1b = *(const bf16x8*)(krowc + key1 * 512 + ((g * 16 + 64 * (s + 4)) ^ sw));
      s1b = __builtin_amdgcn_mfma_f32_16x16x32_bf16(k1b, qf[s + 4], s1b, 0, 0, 0);
    }
    __builtin_amdgcn_s_setprio(0);
    f32x4 st0 = s0a + s0b;
    f32x4 st1 = s1a + s1b;
    // ---- online softmax with deferred rescale (thr=6) ----
    float tmax = -1e30f;
#pragma unroll
    for (int r = 0; r < 4; ++r) {
      tmax = fmaxf(tmax, st0[r]);
      tmax = fmaxf(tmax, st1[r]);
    }
    tmax = fmaxf(tmax, __shfl_xor(tmax, 16, 64));
    tmax = fmaxf(tmax, __shfl_xor(tmax, 32, 64));
    float sm = tmax * SCALE;
    if (__any(sm > m + 6.f)) {
      float mn = fmaxf(m, sm);
      float corr = __expf(m - mn);
#pragma unroll
      for (int f = 0; f < 16; ++f) {
        acc[f][0] *= corr; acc[f][1] *= corr;
        acc[f][2] *= corr; acc[f][3] *= corr;
      }
      l *= corr;
      m = mn;
    }
    float p[8];
    float psum = 0.f;
#pragma unroll
    for (int r = 0; r < 4; ++r) {
      p[r] = __expf(st0[r] * SCALE - m);
      p[4 + r] = __expf(st1[r] * SCALE - m);
      psum += p[r] + p[4 + r];
    }
    psum += __shfl_xor(psum, 16, 64);
    psum += __shfl_xor(psum, 32, 64);
    l += psum;
    // ---- write P^T (bf16) to per-wave LDS: plds[query][key] ----
    {
      uint2 pk0, pk1;
      pk0.x = bf16rne(p[0]) | (bf16rne(p[1]) << 16);
      pk0.y = bf16rne(p[2]) | (bf16rne(p[3]) << 16);
      pk1.x = bf16rne(p[4]) | (bf16rne(p[5]) << 16);
      pk1.y = bf16rne(p[6]) | (bf16rne(p[7]) << 16);
      *(uint2*)(plc + lrow * 80 + g * 8) = pk0;
      *(uint2*)(plc + lrow * 80 + 32 + g * 8) = pk1;
    }
    asm volatile("s_waitcnt lgkmcnt(0)" ::: "memory");
    // ---- O^T += V^T * P (16 MFMAs) ----
    bf16x8 pf = *(const bf16x8*)(plc + lrow * 80 + g * 16);
    __builtin_amdgcn_s_setprio(1);
#pragma unroll
    for (int f = 0; f < 16; ++f) {
      int dim = f * 16 + lrow;
      bf16x8 vf = *(const bf16x8*)(vtc + dim * 80 + g * 16);
      acc[f] = __builtin_amdgcn_mfma_f32_16x16x32_bf16(vf, pf, acc[f], 0, 0, 0);
    }
    __builtin_amdgcn_s_setprio(0);
  }
#undef LOADT
  // ---- epilogue: store unnormalized partial O as bf16 + (m,l) ----
  unsigned short* dstp = ogp + ((size_t)(split * 4 + bh) * LTOT + qi) * DH;
#pragma unroll
  for (int f = 0; f < 16; ++f) {
    uint2 pk;
    pk.x = bf16rne(acc[f][0]) | (bf16rne(acc[f][1]) << 16);
    pk.y = bf16rne(acc[f][2]) | (bf16rne(acc[f][3]) << 16);
    *(uint2*)(dstp + f * 16 + g * 4) = pk;
  }
  if (g == 0) ml[(size_t)(split * 4 + bh) * LTOT + qi] = make_float2(m, l);
}

// Combine splits (weights via LDS) + overlap-add gather + crop -> crop (B,C,64)
__global__ __launch_bounds__(256) void overlap_kernel(
    const unsigned short* __restrict__ ogp, const float2* __restrict__ ml,
    float* __restrict__ crop) {
  __shared__ float w0s[64], w1s[64];
  int r = blockIdx.x;  // 256 = B*h*64 pixels
  int dim = threadIdx.x;
  int p = r & 63;
  int head = (r >> 6) & 1;
  int b = r >> 7;
  int bh = b * 2 + head;
  int y = p >> 3, x = p & 7;
  int py = y + TP, px = x + LP;
  int i0 = max(0, py - 7), i1 = min(7, py);
  int j0 = max(0, px - 7), j1 = min(7, px);
  int ni = i1 - i0 + 1, nj = j1 - j0 + 1, nq = ni * nj;
  if (dim < nq) {
    int iw = i0 + dim / nj, jw = j0 + dim % nj;
    int tok = (py - iw) * 8 + (px - jw);
    int q = (iw * 8 + jw) * 64 + tok;
    float2 a = ml[(size_t)bh * 4096 + q];
    float2 c = ml[(size_t)(4 + bh) * 4096 + q];
    float M = fmaxf(a.x, c.x);
    float e0 = __expf(a.x - M), e1 = __expf(c.x - M);
    float rr = 1.f / (a.y * e0 + c.y * e1);
    w0s[dim] = e0 * rr;
    w1s[dim] = e1 * rr;
  }
  __syncthreads();
  float s = 0.f;
  int t = 0;
  for (int iw = i0; iw <= i1; ++iw)
    for (int jw = j0; jw <= j1; ++jw, ++t) {
      int tok = (py - iw) * 8 + (px - jw);
      int q = (iw * 8 + jw) * 64 + tok;
      size_t e = ((size_t)bh * 4096 + q) * 256 + dim;
      s += w0s[t] * bf2f(ogp[e]) + w1s[t] * bf2f(ogp[(size_t)4 * LTOT * DH + e]);
    }
  float cnt = (float)nq;
  crop[((size_t)b * CC + head * DH + dim) * 64 + p] = s / (cnt + 1e-6f);
}

// out = x_feat + a * (Wproj @ crop + bproj)
__global__ __launch_bounds__(256) void final_kernel(
    const float* __restrict__ crop, const float* __restrict__ Wp,
    const float* __restrict__ bp, const float* __restrict__ x_feat,
    const float* __restrict__ pa, float* __restrict__ out) {
  int blocksPerB = CC >> 2;
  int b = blockIdx.x / blocksPerB;
  int ob = blockIdx.x - b * blocksPerB;
  int o = ob * 4 + (threadIdx.x >> 6);
  int p = threadIdx.x & 63;
  float a = 2.f / (1.f + __expf(-pa[0]));
  const float* xb = crop + (size_t)b * CC * 64;
  const float* wr = Wp + (size_t)o * CC;
  float acc = 0.f;
#pragma unroll 8
  for (int c = 0; c < CC; ++c) acc += wr[c] * xb[c * 64 + p];
  size_t oi = ((size_t)b * CC + o) * 64 + p;
  out[oi] = x_feat[oi] + a * (acc + bp[o]);
}

extern "C" void kernel_launch(void* const* d_in, const int* in_sizes, int n_in,
                              void* d_out, int out_size, void* d_ws, size_t ws_size,
                              hipStream_t stream) {
  const float* x_feat = (const float*)d_in[0];
  const float* z_feat = (const float*)d_in[1];
  const float* Wqkv = (const float*)d_in[2];
  const float* bqkv = (const float*)d_in[3];
  const float* Wqkz = (const float*)d_in[4];
  const float* bqkz = (const float*)d_in[5];
  const float* Wproj = (const float*)d_in[6];
  const float* bproj = (const float*)d_in[7];
  const float* pa = (const float*)d_in[8];
  const float* pbeta = (const float*)d_in[9];
  float* ws = (float*)d_ws;
  float* qkvx = ws;                                        // 196608 f
  float* qkz = ws + 196608;                                // 131072 f
  unsigned short* qgb = (unsigned short*)(ws + 327680);    // 2097152 f
  unsigned short* qgT = (unsigned short*)(ws + 2424832);   // 2097152 f
  unsigned short* ogp = (unsigned short*)(ws + 4521984);   // 4194304 f (2 splits)
  float2* ml = (float2*)(ws + 8716288);                    // 65536 f
  float* crop = ws;                                        // alias qkvx (dead after local_attn)
  float* out = (float*)d_out;

  conv_both_kernel<<<BB * (1536 / 4) + BB * (1024 / 4), 256, 0, stream>>>(
      x_feat, Wqkv, bqkv, qkvx, z_feat, Wqkz, bqkz, qkz);
  local_attn_kernel<<<256, 256, 0, stream>>>(qkvx, qkz, pbeta, qgb, qgT);
  gattn_mfma<<<512, 256, 0, stream>>>(qgb, qgT, ogp, ml);
  overlap_kernel<<<256, 256, 0, stream>>>(ogp, ml, crop);
  final_kernel<<<BB * (CC / 4), 256, 0, stream>>>(crop, Wproj, bproj, x_feat, pa, out);
}

// Round 14
// 216.337 us; speedup vs baseline: 2.6986x; 1.0552x over previous
//
#include <hip/hip_runtime.h>
#include <math.h>

#define BB 2
#define CC 512
#define HEADS 2
#define DH 256
#define NWIN 64
#define LTOT 4096
#define TP 3
#define LP 3
#define SCALE 0.0625f

typedef short bf16x8 __attribute__((ext_vector_type(8)));
typedef float f32x4 __attribute__((ext_vector_type(4)));

__device__ __forceinline__ int refl8(int v) {
  v = v < 0 ? -v : v;
  return v >= 8 ? 14 - v : v;
}

__device__ __forceinline__ unsigned int bf16rne(float x) {
  unsigned int u = __float_as_uint(x);
  return (u + 0x7fffu + ((u >> 16) & 1u)) >> 16;
}

__device__ __forceinline__ float bf2f(unsigned short u) {
  return __uint_as_float(((unsigned int)u) << 16);
}

// Both 1x1 convs in one launch. Y[b,o,p] = sum_c W[o,c] X[b,c,p] + bias[o]
__global__ __launch_bounds__(256) void conv_both_kernel(
    const float* __restrict__ X1, const float* __restrict__ W1,
    const float* __restrict__ b1, float* __restrict__ Y1,
    const float* __restrict__ X2, const float* __restrict__ W2,
    const float* __restrict__ b2, float* __restrict__ Y2) {
  int bidx = blockIdx.x;
  const float *X, *Wm, *bias;
  float* Y;
  int Cout;
  if (bidx < BB * (1536 / 4)) {
    X = X1; Wm = W1; bias = b1; Y = Y1; Cout = 1536;
  } else {
    bidx -= BB * (1536 / 4);
    X = X2; Wm = W2; bias = b2; Y = Y2; Cout = 1024;
  }
  int blocksPerB = Cout >> 2;
  int b = bidx / blocksPerB;
  int ob = bidx - b * blocksPerB;
  int o = ob * 4 + (threadIdx.x >> 6);
  int p = threadIdx.x & 63;
  const float* xb = X + (size_t)b * CC * 64;
  const float* wr = Wm + (size_t)o * CC;
  float acc = 0.f;
#pragma unroll 8
  for (int c = 0; c < CC; ++c) acc += wr[c] * xb[c * 64 + p];
  Y[((size_t)b * Cout + o) * 64 + p] = acc + bias[o];
}

// One block per (b, win, head). Local window attention via MFMA.
// All fragment layouts copied 1:1 from the verified gattn_mfma kernel:
// K/Q rows 512 B XOR-swizzled, V^T/P 80 B stride, S^T = mfma(K,Q).
__global__ __launch_bounds__(256, 1) void local_attn_kernel(
    const float* __restrict__ qkvx, const float* __restrict__ qkz,
    const float* __restrict__ pbeta, unsigned short* __restrict__ qgb,
    unsigned short* __restrict__ qgT) {
  __shared__ unsigned short qk[64 * 256];           // 32 KB: Q staging, then K tiles
  __shared__ unsigned short vt[256 * 40];           // 20 KB: V^T tile, 80 B stride
  __shared__ unsigned short plds[4 * 16 * 2 * 40];  // 10 KB: per-wave P, both tiles
  __shared__ int pixlds[64];
  int bid = blockIdx.x;
  int b = bid >> 7;
  int win = (bid & 127) >> 1;
  int head = bid & 1;
  int tid = threadIdx.x;
  int wave = tid >> 6;
  int lane = tid & 63;
  int lrow = lane & 15;
  int g = lane >> 4;
  int wi = win >> 3, wj = win & 7;
  float beta = log1pf(__expf(pbeta[0])) + 1e-6f;

  const float* qxb = qkvx + (size_t)(b * 1536 + head * DH) * 64;
  const float* kxb = qkvx + (size_t)(b * 1536 + 512 + head * DH) * 64;
  const float* vxb = qkvx + (size_t)(b * 1536 + 1024 + head * DH) * 64;
  const float* qzb = qkz + (size_t)(b * 1024 + head * DH) * 64;
  const float* kzb = qkz + (size_t)(b * 1024 + 512 + head * DH) * 64;

  if (tid < 64) {
    int ry = refl8(wi + (tid >> 3) - TP);
    int rx = refl8(wj + (tid & 7) - LP);
    pixlds[tid] = ry * 8 + rx;
  }
  __syncthreads();
  char* qkc = (char*)qk;
  char* vtc = (char*)vt;
  char* plc = (char*)plds + wave * (16 * 2 * 80);

  // ---- stage Q row-major [64][256] bf16 (XOR-swizzled), read frags ----
  int sq = tid >> 2;   // row 0..63
  int sdg = tid & 3;   // 64-channel group
#define STAGE_Q(SRC)                                                          \
  {                                                                           \
    const float* s0 = (SRC) + pixlds[sq];                                     \
    _Pragma("unroll")                                                         \
    for (int blk = 0; blk < 4; ++blk) {                                       \
      float v[16];                                                            \
      _Pragma("unroll")                                                       \
      for (int j = 0; j < 16; ++j) v[j] = s0[(sdg * 64 + blk * 16 + j) * 64]; \
      unsigned int w[8];                                                      \
      _Pragma("unroll")                                                       \
      for (int j = 0; j < 8; ++j)                                             \
        w[j] = bf16rne(v[2 * j]) | (bf16rne(v[2 * j + 1]) << 16);             \
      int colb = sdg * 128 + blk * 32;                                        \
      *(uint4*)(qkc + sq * 512 + ((colb) ^ ((sq & 7) << 4))) =                \
          make_uint4(w[0], w[1], w[2], w[3]);                                 \
      *(uint4*)(qkc + sq * 512 + ((colb + 16) ^ ((sq & 7) << 4))) =           \
          make_uint4(w[4], w[5], w[6], w[7]);                                 \
    }                                                                         \
  }
  bf16x8 qfx[8], qfz[8];
  int qrow = wave * 16 + lrow;
  int qsw = (qrow & 7) << 4;
  STAGE_Q(qxb);
  __syncthreads();
#pragma unroll
  for (int s = 0; s < 8; ++s)
    qfx[s] = *(const bf16x8*)(qkc + qrow * 512 + ((s * 64 + g * 16) ^ qsw));
  __syncthreads();
  STAGE_Q(qzb);
  __syncthreads();
#pragma unroll
  for (int s = 0; s < 8; ++s)
    qfz[s] = *(const bf16x8*)(qkc + qrow * 512 + ((s * 64 + g * 16) ^ qsw));
  __syncthreads();

  // ---- K tiles (32 keys x 256 ch) staged into first 16 KB of qk ----
  int skey = tid >> 3;  // 0..31
  int skdg = tid & 7;   // 32-channel group
#define STAGE_K(SRC, T2)                                                      \
  {                                                                           \
    const float* s0 = (SRC) + pixlds[(T2) * 32 + skey];                       \
    _Pragma("unroll")                                                         \
    for (int blk = 0; blk < 2; ++blk) {                                       \
      float v[16];                                                            \
      _Pragma("unroll")                                                       \
      for (int j = 0; j < 16; ++j) v[j] = s0[(skdg * 32 + blk * 16 + j) * 64];\
      unsigned int w[8];                                                      \
      _Pragma("unroll")                                                       \
      for (int j = 0; j < 8; ++j)                                             \
        w[j] = bf16rne(v[2 * j]) | (bf16rne(v[2 * j + 1]) << 16);             \
      int colb = skdg * 64 + blk * 32;                                        \
      *(uint4*)(qkc + skey * 512 + ((colb) ^ ((skey & 7) << 4))) =            \
          make_uint4(w[0], w[1], w[2], w[3]);                                 \
      *(uint4*)(qkc + skey * 512 + ((colb + 16) ^ ((skey & 7) << 4))) =       \
          make_uint4(w[4], w[5], w[6], w[7]);                                 \
    }                                                                         \
  }
#define COMPUTE_S(QF, OUT0, OUT1)                                             \
  {                                                                           \
    f32x4 a0 = (f32x4){0.f, 0.f, 0.f, 0.f}, a1 = a0, b0 = a0, b1 = a0;        \
    int sw = (lrow & 7) << 4;                                                 \
    _Pragma("unroll")                                                         \
    for (int s = 0; s < 4; ++s) {                                             \
      bf16x8 k0 = *(const bf16x8*)(qkc + lrow * 512 + ((g * 16 + 64 * s) ^ sw)); \
      a0 = __builtin_amdgcn_mfma_f32_16x16x32_bf16(k0, (QF)[s], a0, 0, 0, 0); \
      bf16x8 k0b = *(const bf16x8*)(qkc + lrow * 512 + ((g * 16 + 64 * (s + 4)) ^ sw)); \
      a1 = __builtin_amdgcn_mfma_f32_16x16x32_bf16(k0b, (QF)[s + 4], a1, 0, 0, 0); \
      bf16x8 k1 = *(const bf16x8*)(qkc + (16 + lrow) * 512 + ((g * 16 + 64 * s) ^ sw)); \
      b0 = __builtin_amdgcn_mfma_f32_16x16x32_bf16(k1, (QF)[s], b0, 0, 0, 0); \
      bf16x8 k1b = *(const bf16x8*)(qkc + (16 + lrow) * 512 + ((g * 16 + 64 * (s + 4)) ^ sw)); \
      b1 = __builtin_amdgcn_mfma_f32_16x16x32_bf16(k1b, (QF)[s + 4], b1, 0, 0, 0); \
    }                                                                         \
    OUT0 = a0 + a1;                                                           \
    OUT1 = b0 + b1;                                                           \
  }
  float lgt[16];
#pragma unroll
  for (int t2 = 0; t2 < 2; ++t2) {
    STAGE_K(kxb, t2);
    __syncthreads();
    f32x4 sx0, sx1;
    COMPUTE_S(qfx, sx0, sx1);
    __syncthreads();
    STAGE_K(kzb, t2);
    __syncthreads();
    f32x4 sz0, sz1;
    COMPUTE_S(qfz, sz0, sz1);
    __syncthreads();
#pragma unroll
    for (int r = 0; r < 4; ++r) {
      lgt[t2 * 8 + r] = SCALE * (sx0[r] + beta * sz0[r]);
      lgt[t2 * 8 + 4 + r] = SCALE * (sx1[r] + beta * sz1[r]);
    }
  }
  // ---- full-row softmax: 16 regs + shfl over key-groups ----
  float mx = -1e30f;
#pragma unroll
  for (int i = 0; i < 16; ++i) mx = fmaxf(mx, lgt[i]);
  mx = fmaxf(mx, __shfl_xor(mx, 16, 64));
  mx = fmaxf(mx, __shfl_xor(mx, 32, 64));
  float p[16];
  float sum = 0.f;
#pragma unroll
  for (int i = 0; i < 16; ++i) {
    p[i] = __expf(lgt[i] - mx);
    sum += p[i];
  }
  sum += __shfl_xor(sum, 16, 64);
  sum += __shfl_xor(sum, 32, 64);
  float rr = 1.f / sum;
#pragma unroll
  for (int i = 0; i < 16; ++i) p[i] *= rr;
#pragma unroll
  for (int t2 = 0; t2 < 2; ++t2) {
    uint2 pk0, pk1;
    pk0.x = bf16rne(p[t2 * 8 + 0]) | (bf16rne(p[t2 * 8 + 1]) << 16);
    pk0.y = bf16rne(p[t2 * 8 + 2]) | (bf16rne(p[t2 * 8 + 3]) << 16);
    pk1.x = bf16rne(p[t2 * 8 + 4]) | (bf16rne(p[t2 * 8 + 5]) << 16);
    pk1.y = bf16rne(p[t2 * 8 + 6]) | (bf16rne(p[t2 * 8 + 7]) << 16);
    *(uint2*)(plc + (lrow * 2 + t2) * 80 + g * 8) = pk0;
    *(uint2*)(plc + (lrow * 2 + t2) * 80 + 32 + g * 8) = pk1;
  }
  asm volatile("s_waitcnt lgkmcnt(0)" ::: "memory");
  // ---- PV over 2 tiles, V^T staged [dim][key] stride 80 ----
  f32x4 acc[16];
#pragma unroll
  for (int f = 0; f < 16; ++f) acc[f] = (f32x4){0.f, 0.f, 0.f, 0.f};
  int svd = tid >> 2;  // dim base 0..63
  int svk = tid & 3;   // 8-key group
#pragma unroll
  for (int t2 = 0; t2 < 2; ++t2) {
    {
      int pk8[8];
#pragma unroll
      for (int j = 0; j < 8; ++j) pk8[j] = pixlds[t2 * 32 + svk * 8 + j];
#pragma unroll
      for (int r = 0; r < 4; ++r) {
        int dim = r * 64 + svd;
        const float* s0 = vxb + (size_t)dim * 64;
        float v[8];
#pragma unroll
        for (int j = 0; j < 8; ++j) v[j] = s0[pk8[j]];
        unsigned int w[4];
#pragma unroll
        for (int j = 0; j < 4; ++j)
          w[j] = bf16rne(v[2 * j]) | (bf16rne(v[2 * j + 1]) << 16);
        *(uint4*)(vtc + dim * 80 + svk * 16) = make_uint4(w[0], w[1], w[2], w[3]);
      }
    }
    __syncthreads();
    bf16x8 pf = *(const bf16x8*)(plc + (lrow * 2 + t2) * 80 + g * 16);
#pragma unroll
    for (int f = 0; f < 16; ++f) {
      int dim = f * 16 + lrow;
      bf16x8 vf = *(const bf16x8*)(vtc + dim * 80 + g * 16);
      acc[f] = __builtin_amdgcn_mfma_f32_16x16x32_bf16(vf, pf, acc[f], 0, 0, 0);
    }
    __syncthreads();
  }
  // ---- epilogue: O^T[dim][q] -> qgb row + qgT scatter ----
  int gtok = win * 64 + wave * 16 + lrow;
  int bh = b * HEADS + head;
  unsigned short* dst = qgb + ((size_t)(bh * LTOT + gtok)) * DH;
  unsigned short* dstT = qgT + (size_t)bh * DH * LTOT + gtok;
#pragma unroll
  for (int f = 0; f < 16; ++f) {
    unsigned int e0 = bf16rne(acc[f][0]), e1 = bf16rne(acc[f][1]);
    unsigned int e2 = bf16rne(acc[f][2]), e3 = bf16rne(acc[f][3]);
    uint2 pk;
    pk.x = e0 | (e1 << 16);
    pk.y = e2 | (e3 << 16);
    *(uint2*)(dst + f * 16 + g * 4) = pk;
    dstT[(size_t)(f * 16 + g * 4 + 0) * LTOT] = (unsigned short)e0;
    dstT[(size_t)(f * 16 + g * 4 + 1) * LTOT] = (unsigned short)e1;
    dstT[(size_t)(f * 16 + g * 4 + 2) * LTOT] = (unsigned short)e2;
    dstT[(size_t)(f * 16 + g * 4 + 3) * LTOT] = (unsigned short)e3;
  }
#undef STAGE_Q
#undef STAGE_K
#undef COMPUTE_S
}

// Global flash attention, split-K 2-way, 4 waves/block, 16 q/wave.
// Round-6 proven config: reg-staged prefetch, 2 barriers/tile, K 512B
// XOR-swizzled, V/P stride 80 B (16B-aligned; 72B misaligns b128 -> 3x slow).
__global__ __launch_bounds__(256, 2) void gattn_mfma(
    const unsigned short* __restrict__ qgb, const unsigned short* __restrict__ qgT,
    unsigned short* __restrict__ ogp, float2* __restrict__ ml) {
  __shared__ unsigned short krow[32 * 256];  // 16 KB, XOR-swizzled rows
  __shared__ unsigned short vt[256 * 40];    // 20 KB, [dim][key], 80 B stride
  __shared__ unsigned short plds[4 * 16 * 40];
  int bid = blockIdx.x;
  int split = bid & 1;
  int qt = (bid >> 1) & 63;
  int bh = bid >> 7;
  int kt0 = split * 64, kt1 = kt0 + 64;
  int qtile = qt * 64;
  int tid = threadIdx.x;
  int wave = tid >> 6;
  int lane = tid & 63;
  int lrow = lane & 15;
  int g = lane >> 4;
  const unsigned short* base = qgb + (size_t)bh * LTOT * DH;
  const unsigned short* baseT = qgT + (size_t)bh * DH * LTOT;
  char* krowc = (char*)krow;
  char* vtc = (char*)vt;
  char* plc = (char*)plds + wave * 16 * 80;

  int qi = qtile + wave * 16 + lrow;
  bf16x8 qf[8];
#pragma unroll
  for (int s = 0; s < 8; ++s)
    qf[s] = *(const bf16x8*)(base + (size_t)qi * DH + s * 32 + g * 8);

  f32x4 acc[16];
#pragma unroll
  for (int f = 0; f < 16; ++f) acc[f] = (f32x4){0.f, 0.f, 0.f, 0.f};
  float m = -1e30f, l = 0.f;

  uint4 kr0, kr1, kr2, kr3, vr0, vr1, vr2, vr3;
  int skey = tid >> 5;  // 0..7
  int sdb = tid & 31;
  int sdim = tid >> 2;  // 0..63
  int sch = tid & 3;

#define LOADT(KT)                                                               \
  {                                                                             \
    const unsigned short* kb = base + (size_t)(KT) * 32 * DH;                   \
    kr0 = *(const uint4*)(kb + (skey + 0) * DH + sdb * 8);                      \
    kr1 = *(const uint4*)(kb + (skey + 8) * DH + sdb * 8);                      \
    kr2 = *(const uint4*)(kb + (skey + 16) * DH + sdb * 8);                     \
    kr3 = *(const uint4*)(kb + (skey + 24) * DH + sdb * 8);                     \
    const unsigned short* vb = baseT + (size_t)(KT) * 32 + sch * 8;             \
    vr0 = *(const uint4*)(vb + (size_t)(sdim + 0) * LTOT);                      \
    vr1 = *(const uint4*)(vb + (size_t)(sdim + 64) * LTOT);                     \
    vr2 = *(const uint4*)(vb + (size_t)(sdim + 128) * LTOT);                    \
    vr3 = *(const uint4*)(vb + (size_t)(sdim + 192) * LTOT);                    \
  }

  LOADT(kt0);
  for (int kt = kt0; kt < kt1; ++kt) {
    __syncthreads();  // all waves done reading LDS of previous tile
    // ---- write staged regs -> LDS ----
    *(uint4*)(krowc + (skey + 0) * 512 + ((sdb * 16) ^ (((skey + 0) & 7) << 4))) = kr0;
    *(uint4*)(krowc + (skey + 8) * 512 + ((sdb * 16) ^ (((skey + 8) & 7) << 4))) = kr1;
    *(uint4*)(krowc + (skey + 16) * 512 + ((sdb * 16) ^ (((skey + 16) & 7) << 4))) = kr2;
    *(uint4*)(krowc + (skey + 24) * 512 + ((sdb * 16) ^ (((skey + 24) & 7) << 4))) = kr3;
    *(uint4*)(vtc + (sdim + 0) * 80 + sch * 16) = vr0;
    *(uint4*)(vtc + (sdim + 64) * 80 + sch * 16) = vr1;
    *(uint4*)(vtc + (sdim + 128) * 80 + sch * 16) = vr2;
    *(uint4*)(vtc + (sdim + 192) * 80 + sch * 16) = vr3;
    // ---- prefetch next tile into regs (latency hides under compute) ----
    if (kt + 1 < kt1) LOADT(kt + 1);
    __syncthreads();  // staged LDS visible
    // ---- S^T = K * Q^T (16 MFMAs, 4 independent chains) ----
    f32x4 s0a = (f32x4){0.f, 0.f, 0.f, 0.f}, s0b = s0a, s1a = s0a, s1b = s0a;
    int key0 = lrow, key1 = 16 + lrow;
    int sw = (lrow & 7) << 4;
    __builtin_amdgcn_s_setprio(1);
#pragma unroll
    for (int s = 0; s < 4; ++s) {
      bf16x8 k0 = *(const bf16x8*)(krowc + key0 * 512 + ((g * 16 + 64 * s) ^ sw));
      s0a = __builtin_amdgcn_mfma_f32_16x16x32_bf16(k0, qf[s], s0a, 0, 0, 0);
      bf16x8 k0b = *(const bf16x8*)(krowc + key0 * 512 + ((g * 16 + 64 * (s + 4)) ^ sw));
      s0b = __builtin_amdgcn_mfma_f32_16x16x32_bf16(k0b, qf[s + 4], s0b, 0, 0, 0);
      bf16x8 k1 = *(const bf16x8*)(krowc + key1 * 512 + ((g * 16 + 64 * s) ^ sw));
      s1a = __builtin_amdgcn_mfma_f32_16x16x32_bf16(k1, qf[s], s1a, 0, 0, 0);
      bf16x8 k1b = *(const bf16x8*)(krowc + key1 * 512 + ((g * 16 + 64 * (s + 4)) ^ sw));
      s1b = __builtin_amdgcn_mfma_f32_16x16x32_bf16(k1b, qf[s + 4], s1b, 0, 0, 0);
    }
    __builtin_amdgcn_s_setprio(0);
    f32x4 st0 = s0a + s0b;
    f32x4 st1 = s1a + s1b;
    // ---- online softmax with deferred rescale (thr=6) ----
    float tmax = -1e30f;
#pragma unroll
    for (int r = 0; r < 4; ++r) {
      tmax = fmaxf(tmax, st0[r]);
      tmax = fmaxf(tmax, st1[r]);
    }
    tmax = fmaxf(tmax, __shfl_xor(tmax, 16, 64));
    tmax = fmaxf(tmax, __shfl_xor(tmax, 32, 64));
    float sm = tmax * SCALE;
    if (__any(sm > m + 6.f)) {
      float mn = fmaxf(m, sm);
      float corr = __expf(m - mn);
#pragma unroll
      for (int f = 0; f < 16; ++f) {
        acc[f][0] *= corr; acc[f][1] *= corr;
        acc[f][2] *= corr; acc[f][3] *= corr;
      }
      l *= corr;
      m = mn;
    }
    float p[8];
    float psum = 0.f;
#pragma unroll
    for (int r = 0; r < 4; ++r) {
      p[r] = __expf(st0[r] * SCALE - m);
      p[4 + r] = __expf(st1[r] * SCALE - m);
      psum += p[r] + p[4 + r];
    }
    psum += __shfl_xor(psum, 16, 64);
    psum += __shfl_xor(psum, 32, 64);
    l += psum;
    // ---- write P^T (bf16) to per-wave LDS: plds[query][key] ----
    {
      uint2 pk0, pk1;
      pk0.x = bf16rne(p[0]) | (bf16rne(p[1]) << 16);
      pk0.y = bf16rne(p[2]) | (bf16rne(p[3]) << 16);
      pk1.x = bf16rne(p[4]) | (bf16rne(p[5]) << 16);
      pk1.y = bf16rne(p[6]) | (bf16rne(p[7]) << 16);
      *(uint2*)(plc + lrow * 80 + g * 8) = pk0;
      *(uint2*)(plc + lrow * 80 + 32 + g * 8) = pk1;
    }
    asm volatile("s_waitcnt lgkmcnt(0)" ::: "memory");
    // ---- O^T += V^T * P (16 MFMAs) ----
    bf16x8 pf = *(const bf16x8*)(plc + lrow * 80 + g * 16);
    __builtin_amdgcn_s_setprio(1);
#pragma unroll
    for (int f = 0; f < 16; ++f) {
      int dim = f * 16 + lrow;
      bf16x8 vf = *(const bf16x8*)(vtc + dim * 80 + g * 16);
      acc[f] = __builtin_amdgcn_mfma_f32_16x16x32_bf16(vf, pf, acc[f], 0, 0, 0);
    }
    __builtin_amdgcn_s_setprio(0);
  }
#undef LOADT
  // ---- epilogue: store unnormalized partial O as bf16 + (m,l) ----
  unsigned short* dstp = ogp + ((size_t)(split * 4 + bh) * LTOT + qi) * DH;
#pragma unroll
  for (int f = 0; f < 16; ++f) {
    uint2 pk;
    pk.x = bf16rne(acc[f][0]) | (bf16rne(acc[f][1]) << 16);
    pk.y = bf16rne(acc[f][2]) | (bf16rne(acc[f][3]) << 16);
    *(uint2*)(dstp + f * 16 + g * 4) = pk;
  }
  if (g == 0) ml[(size_t)(split * 4 + bh) * LTOT + qi] = make_float2(m, l);
}

// Combine splits + overlap-add gather + crop. Vectorized: lane = 4-dim group
// (uint2 loads, 512B/wave-op), each of 4 waves handles a strided quarter of
// the covering windows, partials reduced via LDS.
__global__ __launch_bounds__(256) void overlap_kernel(
    const unsigned short* __restrict__ ogp, const float2* __restrict__ ml,
    float* __restrict__ crop) {
  __shared__ float w0s[64], w1s[64];
  __shared__ float part[4 * 256];
  int r = blockIdx.x;  // 256 = B*h*64 pixels
  int tid = threadIdx.x;
  int w4 = tid >> 6;
  int dg = tid & 63;  // dim group: dims dg*4 .. dg*4+3
  int p = r & 63;
  int head = (r >> 6) & 1;
  int b = r >> 7;
  int bh = b * 2 + head;
  int y = p >> 3, x = p & 7;
  int py = y + TP, px = x + LP;
  int i0 = max(0, py - 7), i1 = min(7, py);
  int j0 = max(0, px - 7), j1 = min(7, px);
  int ni = i1 - i0 + 1, nj = j1 - j0 + 1, nq = ni * nj;
  if (tid < nq) {
    int iw = i0 + tid / nj, jw = j0 + tid % nj;
    int tok = (py - iw) * 8 + (px - jw);
    int q = (iw * 8 + jw) * 64 + tok;
    float2 a = ml[(size_t)bh * 4096 + q];
    float2 c = ml[(size_t)(4 + bh) * 4096 + q];
    float M = fmaxf(a.x, c.x);
    float e0 = __expf(a.x - M), e1 = __expf(c.x - M);
    float rr = 1.f / (a.y * e0 + c.y * e1);
    w0s[tid] = e0 * rr;
    w1s[tid] = e1 * rr;
  }
  __syncthreads();
  float a0 = 0.f, a1 = 0.f, a2 = 0.f, a3 = 0.f;
  for (int t = w4; t < nq; t += 4) {
    int iw = i0 + t / nj, jw = j0 + t % nj;
    int tok = (py - iw) * 8 + (px - jw);
    int q = (iw * 8 + jw) * 64 + tok;
    size_t e = ((size_t)bh * 4096 + q) * 256 + dg * 4;
    uint2 o0 = *(const uint2*)(ogp + e);
    uint2 o1 = *(const uint2*)(ogp + (size_t)4 * LTOT * DH + e);
    float cw0 = w0s[t], cw1 = w1s[t];
    a0 += cw0 * bf2f((unsigned short)(o0.x & 0xffff)) + cw1 * bf2f((unsigned short)(o1.x & 0xffff));
    a1 += cw0 * bf2f((unsigned short)(o0.x >> 16)) + cw1 * bf2f((unsigned short)(o1.x >> 16));
    a2 += cw0 * bf2f((unsigned short)(o0.y & 0xffff)) + cw1 * bf2f((unsigned short)(o1.y & 0xffff));
    a3 += cw0 * bf2f((unsigned short)(o0.y >> 16)) + cw1 * bf2f((unsigned short)(o1.y >> 16));
  }
  part[w4 * 256 + dg * 4 + 0] = a0;
  part[w4 * 256 + dg * 4 + 1] = a1;
  part[w4 * 256 + dg * 4 + 2] = a2;
  part[w4 * 256 + dg * 4 + 3] = a3;
  __syncthreads();
  float s = part[tid] + part[256 + tid] + part[512 + tid] + part[768 + tid];
  float cnt = (float)nq;
  crop[((size_t)b * CC + head * DH + tid) * 64 + p] = s / (cnt + 1e-6f);
}

// out = x_feat + a * (Wproj @ crop + bproj)
__global__ __launch_bounds__(256) void final_kernel(
    const float* __restrict__ crop, const float* __restrict__ Wp,
    const float* __restrict__ bp, const float* __restrict__ x_feat,
    const float* __restrict__ pa, float* __restrict__ out) {
  int blocksPerB = CC >> 2;
  int b = blockIdx.x / blocksPerB;
  int ob = blockIdx.x - b * blocksPerB;
  int o = ob * 4 + (threadIdx.x >> 6);
  int p = threadIdx.x & 63;
  float a = 2.f / (1.f + __expf(-pa[0]));
  const float* xb = crop + (size_t)b * CC * 64;
  const float* wr = Wp + (size_t)o * CC;
  float acc = 0.f;
#pragma unroll 8
  for (int c = 0; c < CC; ++c) acc += wr[c] * xb[c * 64 + p];
  size_t oi = ((size_t)b * CC + o) * 64 + p;
  out[oi] = x_feat[oi] + a * (acc + bp[o]);
}

extern "C" void kernel_launch(void* const* d_in, const int* in_sizes, int n_in,
                              void* d_out, int out_size, void* d_ws, size_t ws_size,
                              hipStream_t stream) {
  const float* x_feat = (const float*)d_in[0];
  const float* z_feat = (const float*)d_in[1];
  const float* Wqkv = (const float*)d_in[2];
  const float* bqkv = (const float*)d_in[3];
  const float* Wqkz = (const float*)d_in[4];
  const float* bqkz = (const float*)d_in[5];
  const float* Wproj = (const float*)d_in[6];
  const float* bproj = (const float*)d_in[7];
  const float* pa = (const float*)d_in[8];
  const float* pbeta = (const float*)d_in[9];
  float* ws = (float*)d_ws;
  float* qkvx = ws;                                        // 196608 f
  float* qkz = ws + 196608;                                // 131072 f
  unsigned short* qgb = (unsigned short*)(ws + 327680);    // 2097152 f
  unsigned short* qgT = (unsigned short*)(ws + 2424832);   // 2097152 f
  unsigned short* ogp = (unsigned short*)(ws + 4521984);   // 4194304 f (2 splits)
  float2* ml = (float2*)(ws + 8716288);                    // 65536 f
  float* crop = ws;                                        // alias qkvx (dead after local_attn)
  float* out = (float*)d_out;

  conv_both_kernel<<<BB * (1536 / 4) + BB * (1024 / 4), 256, 0, stream>>>(
      x_feat, Wqkv, bqkv, qkvx, z_feat, Wqkz, bqkz, qkz);
  local_attn_kernel<<<256, 256, 0, stream>>>(qkvx, qkz, pbeta, qgb, qgT);
  gattn_mfma<<<512, 256, 0, stream>>>(qgb, qgT, ogp, ml);
  overlap_kernel<<<256, 256, 0, stream>>>(ogp, ml, crop);
  final_kernel<<<BB * (CC / 4), 256, 0, stream>>>(crop, Wproj, bproj, x_feat, pa, out);
}

// Round 15
// 215.756 us; speedup vs baseline: 2.7059x; 1.0027x over previous
//
#include <hip/hip_runtime.h>
#include <math.h>

#define BB 2
#define CC 512
#define HEADS 2
#define DH 256
#define NWIN 64
#define LTOT 4096
#define TP 3
#define LP 3
#define SCALE 0.0625f

typedef short bf16x8 __attribute__((ext_vector_type(8)));
typedef float f32x4 __attribute__((ext_vector_type(4)));

__device__ __forceinline__ int refl8(int v) {
  v = v < 0 ? -v : v;
  return v >= 8 ? 14 - v : v;
}

__device__ __forceinline__ unsigned int bf16rne(float x) {
  unsigned int u = __float_as_uint(x);
  return (u + 0x7fffu + ((u >> 16) & 1u)) >> 16;
}

__device__ __forceinline__ float bf2f(unsigned short u) {
  return __uint_as_float(((unsigned int)u) << 16);
}

// Both 1x1 convs in one launch. Y[b,o,p] = sum_c W[o,c] X[b,c,p] + bias[o]
__global__ __launch_bounds__(256) void conv_both_kernel(
    const float* __restrict__ X1, const float* __restrict__ W1,
    const float* __restrict__ b1, float* __restrict__ Y1,
    const float* __restrict__ X2, const float* __restrict__ W2,
    const float* __restrict__ b2, float* __restrict__ Y2) {
  int bidx = blockIdx.x;
  const float *X, *Wm, *bias;
  float* Y;
  int Cout;
  if (bidx < BB * (1536 / 4)) {
    X = X1; Wm = W1; bias = b1; Y = Y1; Cout = 1536;
  } else {
    bidx -= BB * (1536 / 4);
    X = X2; Wm = W2; bias = b2; Y = Y2; Cout = 1024;
  }
  int blocksPerB = Cout >> 2;
  int b = bidx / blocksPerB;
  int ob = bidx - b * blocksPerB;
  int o = ob * 4 + (threadIdx.x >> 6);
  int p = threadIdx.x & 63;
  const float* xb = X + (size_t)b * CC * 64;
  const float* wr = Wm + (size_t)o * CC;
  float acc = 0.f;
#pragma unroll 8
  for (int c = 0; c < CC; ++c) acc += wr[c] * xb[c * 64 + p];
  Y[((size_t)b * Cout + o) * 64 + p] = acc + bias[o];
}

// One block per (b, win, head). Local window attention via MFMA.
// Fragment layouts copied 1:1 from gattn_mfma.
__global__ __launch_bounds__(256, 1) void local_attn_kernel(
    const float* __restrict__ qkvx, const float* __restrict__ qkz,
    const float* __restrict__ pbeta, unsigned short* __restrict__ qgb,
    unsigned short* __restrict__ qgT) {
  __shared__ unsigned short qk[64 * 256];           // 32 KB: Q staging, then K tiles
  __shared__ unsigned short vt[256 * 40];           // 20 KB: V^T tile, 80 B stride
  __shared__ unsigned short plds[4 * 16 * 2 * 40];  // 10 KB: per-wave P, both tiles
  __shared__ int pixlds[64];
  int bid = blockIdx.x;
  int b = bid >> 7;
  int win = (bid & 127) >> 1;
  int head = bid & 1;
  int tid = threadIdx.x;
  int wave = tid >> 6;
  int lane = tid & 63;
  int lrow = lane & 15;
  int g = lane >> 4;
  int wi = win >> 3, wj = win & 7;
  float beta = log1pf(__expf(pbeta[0])) + 1e-6f;

  const float* qxb = qkvx + (size_t)(b * 1536 + head * DH) * 64;
  const float* kxb = qkvx + (size_t)(b * 1536 + 512 + head * DH) * 64;
  const float* vxb = qkvx + (size_t)(b * 1536 + 1024 + head * DH) * 64;
  const float* qzb = qkz + (size_t)(b * 1024 + head * DH) * 64;
  const float* kzb = qkz + (size_t)(b * 1024 + 512 + head * DH) * 64;

  if (tid < 64) {
    int ry = refl8(wi + (tid >> 3) - TP);
    int rx = refl8(wj + (tid & 7) - LP);
    pixlds[tid] = ry * 8 + rx;
  }
  __syncthreads();
  char* qkc = (char*)qk;
  char* vtc = (char*)vt;
  char* plc = (char*)plds + wave * (16 * 2 * 80);

  // ---- stage Q row-major [64][256] bf16 (XOR-swizzled), read frags ----
  int sq = tid >> 2;   // row 0..63
  int sdg = tid & 3;   // 64-channel group
#define STAGE_Q(SRC)                                                          \
  {                                                                           \
    const float* s0 = (SRC) + pixlds[sq];                                     \
    _Pragma("unroll")                                                         \
    for (int blk = 0; blk < 4; ++blk) {                                       \
      float v[16];                                                            \
      _Pragma("unroll")                                                       \
      for (int j = 0; j < 16; ++j) v[j] = s0[(sdg * 64 + blk * 16 + j) * 64]; \
      unsigned int w[8];                                                      \
      _Pragma("unroll")                                                       \
      for (int j = 0; j < 8; ++j)                                             \
        w[j] = bf16rne(v[2 * j]) | (bf16rne(v[2 * j + 1]) << 16);             \
      int colb = sdg * 128 + blk * 32;                                        \
      *(uint4*)(qkc + sq * 512 + ((colb) ^ ((sq & 7) << 4))) =                \
          make_uint4(w[0], w[1], w[2], w[3]);                                 \
      *(uint4*)(qkc + sq * 512 + ((colb + 16) ^ ((sq & 7) << 4))) =           \
          make_uint4(w[4], w[5], w[6], w[7]);                                 \
    }                                                                         \
  }
  bf16x8 qfx[8], qfz[8];
  int qrow = wave * 16 + lrow;
  int qsw = (qrow & 7) << 4;
  STAGE_Q(qxb);
  __syncthreads();
#pragma unroll
  for (int s = 0; s < 8; ++s)
    qfx[s] = *(const bf16x8*)(qkc + qrow * 512 + ((s * 64 + g * 16) ^ qsw));
  __syncthreads();
  STAGE_Q(qzb);
  __syncthreads();
#pragma unroll
  for (int s = 0; s < 8; ++s)
    qfz[s] = *(const bf16x8*)(qkc + qrow * 512 + ((s * 64 + g * 16) ^ qsw));
  __syncthreads();

  // ---- K tiles (32 keys x 256 ch) staged into first 16 KB of qk ----
  int skey = tid >> 3;  // 0..31
  int skdg = tid & 7;   // 32-channel group
#define STAGE_K(SRC, T2)                                                      \
  {                                                                           \
    const float* s0 = (SRC) + pixlds[(T2) * 32 + skey];                       \
    _Pragma("unroll")                                                         \
    for (int blk = 0; blk < 2; ++blk) {                                       \
      float v[16];                                                            \
      _Pragma("unroll")                                                       \
      for (int j = 0; j < 16; ++j) v[j] = s0[(skdg * 32 + blk * 16 + j) * 64];\
      unsigned int w[8];                                                      \
      _Pragma("unroll")                                                       \
      for (int j = 0; j < 8; ++j)                                             \
        w[j] = bf16rne(v[2 * j]) | (bf16rne(v[2 * j + 1]) << 16);             \
      int colb = skdg * 64 + blk * 32;                                        \
      *(uint4*)(qkc + skey * 512 + ((colb) ^ ((skey & 7) << 4))) =            \
          make_uint4(w[0], w[1], w[2], w[3]);                                 \
      *(uint4*)(qkc + skey * 512 + ((colb + 16) ^ ((skey & 7) << 4))) =       \
          make_uint4(w[4], w[5], w[6], w[7]);                                 \
    }                                                                         \
  }
#define COMPUTE_S(QF, OUT0, OUT1)                                             \
  {                                                                           \
    f32x4 a0 = (f32x4){0.f, 0.f, 0.f, 0.f}, a1 = a0, b0 = a0, b1 = a0;        \
    int sw = (lrow & 7) << 4;                                                 \
    _Pragma("unroll")                                                         \
    for (int s = 0; s < 4; ++s) {                                             \
      bf16x8 k0 = *(const bf16x8*)(qkc + lrow * 512 + ((g * 16 + 64 * s) ^ sw)); \
      a0 = __builtin_amdgcn_mfma_f32_16x16x32_bf16(k0, (QF)[s], a0, 0, 0, 0); \
      bf16x8 k0b = *(const bf16x8*)(qkc + lrow * 512 + ((g * 16 + 64 * (s + 4)) ^ sw)); \
      a1 = __builtin_amdgcn_mfma_f32_16x16x32_bf16(k0b, (QF)[s + 4], a1, 0, 0, 0); \
      bf16x8 k1 = *(const bf16x8*)(qkc + (16 + lrow) * 512 + ((g * 16 + 64 * s) ^ sw)); \
      b0 = __builtin_amdgcn_mfma_f32_16x16x32_bf16(k1, (QF)[s], b0, 0, 0, 0); \
      bf16x8 k1b = *(const bf16x8*)(qkc + (16 + lrow) * 512 + ((g * 16 + 64 * (s + 4)) ^ sw)); \
      b1 = __builtin_amdgcn_mfma_f32_16x16x32_bf16(k1b, (QF)[s + 4], b1, 0, 0, 0); \
    }                                                                         \
    OUT0 = a0 + a1;                                                           \
    OUT1 = b0 + b1;                                                           \
  }
  float lgt[16];
#pragma unroll
  for (int t2 = 0; t2 < 2; ++t2) {
    STAGE_K(kxb, t2);
    __syncthreads();
    f32x4 sx0, sx1;
    COMPUTE_S(qfx, sx0, sx1);
    __syncthreads();
    STAGE_K(kzb, t2);
    __syncthreads();
    f32x4 sz0, sz1;
    COMPUTE_S(qfz, sz0, sz1);
    __syncthreads();
#pragma unroll
    for (int r = 0; r < 4; ++r) {
      lgt[t2 * 8 + r] = SCALE * (sx0[r] + beta * sz0[r]);
      lgt[t2 * 8 + 4 + r] = SCALE * (sx1[r] + beta * sz1[r]);
    }
  }
  // ---- full-row softmax: 16 regs + shfl over key-groups ----
  float mx = -1e30f;
#pragma unroll
  for (int i = 0; i < 16; ++i) mx = fmaxf(mx, lgt[i]);
  mx = fmaxf(mx, __shfl_xor(mx, 16, 64));
  mx = fmaxf(mx, __shfl_xor(mx, 32, 64));
  float p[16];
  float sum = 0.f;
#pragma unroll
  for (int i = 0; i < 16; ++i) {
    p[i] = __expf(lgt[i] - mx);
    sum += p[i];
  }
  sum += __shfl_xor(sum, 16, 64);
  sum += __shfl_xor(sum, 32, 64);
  float rr = 1.f / sum;
#pragma unroll
  for (int i = 0; i < 16; ++i) p[i] *= rr;
#pragma unroll
  for (int t2 = 0; t2 < 2; ++t2) {
    uint2 pk0, pk1;
    pk0.x = bf16rne(p[t2 * 8 + 0]) | (bf16rne(p[t2 * 8 + 1]) << 16);
    pk0.y = bf16rne(p[t2 * 8 + 2]) | (bf16rne(p[t2 * 8 + 3]) << 16);
    pk1.x = bf16rne(p[t2 * 8 + 4]) | (bf16rne(p[t2 * 8 + 5]) << 16);
    pk1.y = bf16rne(p[t2 * 8 + 6]) | (bf16rne(p[t2 * 8 + 7]) << 16);
    *(uint2*)(plc + (lrow * 2 + t2) * 80 + g * 8) = pk0;
    *(uint2*)(plc + (lrow * 2 + t2) * 80 + 32 + g * 8) = pk1;
  }
  asm volatile("s_waitcnt lgkmcnt(0)" ::: "memory");
  // ---- PV over 2 tiles, V^T staged [dim][key] stride 80 ----
  // bank-spread mapping: sdim low bits from lane, high bits from wave;
  // per-quarter banks = 20*d_low mod 32 -> 2-way (free).
  f32x4 acc[16];
#pragma unroll
  for (int f = 0; f < 16; ++f) acc[f] = (f32x4){0.f, 0.f, 0.f, 0.f};
  int svd = (tid & 15) | ((tid >> 6) << 4);  // dim base 0..63
  int svk = (tid >> 4) & 3;                  // 8-key group
#pragma unroll
  for (int t2 = 0; t2 < 2; ++t2) {
    {
      int pk8[8];
#pragma unroll
      for (int j = 0; j < 8; ++j) pk8[j] = pixlds[t2 * 32 + svk * 8 + j];
#pragma unroll
      for (int r = 0; r < 4; ++r) {
        int dim = r * 64 + svd;
        const float* s0 = vxb + (size_t)dim * 64;
        float v[8];
#pragma unroll
        for (int j = 0; j < 8; ++j) v[j] = s0[pk8[j]];
        unsigned int w[4];
#pragma unroll
        for (int j = 0; j < 4; ++j)
          w[j] = bf16rne(v[2 * j]) | (bf16rne(v[2 * j + 1]) << 16);
        *(uint4*)(vtc + dim * 80 + svk * 16) = make_uint4(w[0], w[1], w[2], w[3]);
      }
    }
    __syncthreads();
    bf16x8 pf = *(const bf16x8*)(plc + (lrow * 2 + t2) * 80 + g * 16);
#pragma unroll
    for (int f = 0; f < 16; ++f) {
      int dim = f * 16 + lrow;
      bf16x8 vf = *(const bf16x8*)(vtc + dim * 80 + g * 16);
      acc[f] = __builtin_amdgcn_mfma_f32_16x16x32_bf16(vf, pf, acc[f], 0, 0, 0);
    }
    __syncthreads();
  }
  // ---- epilogue: O^T[dim][q] -> qgb row + qgT scatter ----
  int gtok = win * 64 + wave * 16 + lrow;
  int bh = b * HEADS + head;
  unsigned short* dst = qgb + ((size_t)(bh * LTOT + gtok)) * DH;
  unsigned short* dstT = qgT + (size_t)bh * DH * LTOT + gtok;
#pragma unroll
  for (int f = 0; f < 16; ++f) {
    unsigned int e0 = bf16rne(acc[f][0]), e1 = bf16rne(acc[f][1]);
    unsigned int e2 = bf16rne(acc[f][2]), e3 = bf16rne(acc[f][3]);
    uint2 pk;
    pk.x = e0 | (e1 << 16);
    pk.y = e2 | (e3 << 16);
    *(uint2*)(dst + f * 16 + g * 4) = pk;
    dstT[(size_t)(f * 16 + g * 4 + 0) * LTOT] = (unsigned short)e0;
    dstT[(size_t)(f * 16 + g * 4 + 1) * LTOT] = (unsigned short)e1;
    dstT[(size_t)(f * 16 + g * 4 + 2) * LTOT] = (unsigned short)e2;
    dstT[(size_t)(f * 16 + g * 4 + 3) * LTOT] = (unsigned short)e3;
  }
#undef STAGE_Q
#undef STAGE_K
#undef COMPUTE_S
}

// Global flash attention, split-K 2-way, 4 waves/block, 16 q/wave.
// Round-6 proven config + bank-spread V-stage mapping (r15).
__global__ __launch_bounds__(256, 2) void gattn_mfma(
    const unsigned short* __restrict__ qgb, const unsigned short* __restrict__ qgT,
    unsigned short* __restrict__ ogp, float2* __restrict__ ml) {
  __shared__ unsigned short krow[32 * 256];  // 16 KB, XOR-swizzled rows
  __shared__ unsigned short vt[256 * 40];    // 20 KB, [dim][key], 80 B stride
  __shared__ unsigned short plds[4 * 16 * 40];
  int bid = blockIdx.x;
  int split = bid & 1;
  int qt = (bid >> 1) & 63;
  int bh = bid >> 7;
  int kt0 = split * 64, kt1 = kt0 + 64;
  int qtile = qt * 64;
  int tid = threadIdx.x;
  int wave = tid >> 6;
  int lane = tid & 63;
  int lrow = lane & 15;
  int g = lane >> 4;
  const unsigned short* base = qgb + (size_t)bh * LTOT * DH;
  const unsigned short* baseT = qgT + (size_t)bh * DH * LTOT;
  char* krowc = (char*)krow;
  char* vtc = (char*)vt;
  char* plc = (char*)plds + wave * 16 * 80;

  int qi = qtile + wave * 16 + lrow;
  bf16x8 qf[8];
#pragma unroll
  for (int s = 0; s < 8; ++s)
    qf[s] = *(const bf16x8*)(base + (size_t)qi * DH + s * 32 + g * 8);

  f32x4 acc[16];
#pragma unroll
  for (int f = 0; f < 16; ++f) acc[f] = (f32x4){0.f, 0.f, 0.f, 0.f};
  float m = -1e30f, l = 0.f;

  uint4 kr0, kr1, kr2, kr3, vr0, vr1, vr2, vr3;
  int skey = tid >> 5;  // 0..7
  int sdb = tid & 31;
  // bank-spread V mapping: within a wave sdim spans w*16..w*16+15 (same
  // 64B global segments as before -> coalescing unchanged), per-quarter
  // LDS-write banks 20*d_low mod 32 -> 2-way (free).
  int sdim = (tid & 15) | ((tid >> 6) << 4);  // 0..63
  int sch = (tid >> 4) & 3;

#define LOADT(KT)                                                               \
  {                                                                             \
    const unsigned short* kb = base + (size_t)(KT) * 32 * DH;                   \
    kr0 = *(const uint4*)(kb + (skey + 0) * DH + sdb * 8);                      \
    kr1 = *(const uint4*)(kb + (skey + 8) * DH + sdb * 8);                      \
    kr2 = *(const uint4*)(kb + (skey + 16) * DH + sdb * 8);                     \
    kr3 = *(const uint4*)(kb + (skey + 24) * DH + sdb * 8);                     \
    const unsigned short* vb = baseT + (size_t)(KT) * 32 + sch * 8;             \
    vr0 = *(const uint4*)(vb + (size_t)(sdim + 0) * LTOT);                      \
    vr1 = *(const uint4*)(vb + (size_t)(sdim + 64) * LTOT);                     \
    vr2 = *(const uint4*)(vb + (size_t)(sdim + 128) * LTOT);                    \
    vr3 = *(const uint4*)(vb + (size_t)(sdim + 192) * LTOT);                    \
  }

  LOADT(kt0);
  for (int kt = kt0; kt < kt1; ++kt) {
    __syncthreads();  // all waves done reading LDS of previous tile
    // ---- write staged regs -> LDS ----
    *(uint4*)(krowc + (skey + 0) * 512 + ((sdb * 16) ^ (((skey + 0) & 7) << 4))) = kr0;
    *(uint4*)(krowc + (skey + 8) * 512 + ((sdb * 16) ^ (((skey + 8) & 7) << 4))) = kr1;
    *(uint4*)(krowc + (skey + 16) * 512 + ((sdb * 16) ^ (((skey + 16) & 7) << 4))) = kr2;
    *(uint4*)(krowc + (skey + 24) * 512 + ((sdb * 16) ^ (((skey + 24) & 7) << 4))) = kr3;
    *(uint4*)(vtc + (sdim + 0) * 80 + sch * 16) = vr0;
    *(uint4*)(vtc + (sdim + 64) * 80 + sch * 16) = vr1;
    *(uint4*)(vtc + (sdim + 128) * 80 + sch * 16) = vr2;
    *(uint4*)(vtc + (sdim + 192) * 80 + sch * 16) = vr3;
    // ---- prefetch next tile into regs (latency hides under compute) ----
    if (kt + 1 < kt1) LOADT(kt + 1);
    __syncthreads();  // staged LDS visible
    // ---- S^T = K * Q^T (16 MFMAs, 4 independent chains) ----
    f32x4 s0a = (f32x4){0.f, 0.f, 0.f, 0.f}, s0b = s0a, s1a = s0a, s1b = s0a;
    int key0 = lrow, key1 = 16 + lrow;
    int sw = (lrow & 7) << 4;
    __builtin_amdgcn_s_setprio(1);
#pragma unroll
    for (int s = 0; s < 4; ++s) {
      bf16x8 k0 = *(const bf16x8*)(krowc + key0 * 512 + ((g * 16 + 64 * s) ^ sw));
      s0a = __builtin_amdgcn_mfma_f32_16x16x32_bf16(k0, qf[s], s0a, 0, 0, 0);
      bf16x8 k0b = *(const bf16x8*)(krowc + key0 * 512 + ((g * 16 + 64 * (s + 4)) ^ sw));
      s0b = __builtin_amdgcn_mfma_f32_16x16x32_bf16(k0b, qf[s + 4], s0b, 0, 0, 0);
      bf16x8 k1 = *(const bf16x8*)(krowc + key1 * 512 + ((g * 16 + 64 * s) ^ sw));
      s1a = __builtin_amdgcn_mfma_f32_16x16x32_bf16(k1, qf[s], s1a, 0, 0, 0);
      bf16x8 k1b = *(const bf16x8*)(krowc + key1 * 512 + ((g * 16 + 64 * (s + 4)) ^ sw));
      s1b = __builtin_amdgcn_mfma_f32_16x16x32_bf16(k1b, qf[s + 4], s1b, 0, 0, 0);
    }
    __builtin_amdgcn_s_setprio(0);
    f32x4 st0 = s0a + s0b;
    f32x4 st1 = s1a + s1b;
    // ---- online softmax with deferred rescale (thr=6) ----
    float tmax = -1e30f;
#pragma unroll
    for (int r = 0; r < 4; ++r) {
      tmax = fmaxf(tmax, st0[r]);
      tmax = fmaxf(tmax, st1[r]);
    }
    tmax = fmaxf(tmax, __shfl_xor(tmax, 16, 64));
    tmax = fmaxf(tmax, __shfl_xor(tmax, 32, 64));
    float sm = tmax * SCALE;
    if (__any(sm > m + 6.f)) {
      float mn = fmaxf(m, sm);
      float corr = __expf(m - mn);
#pragma unroll
      for (int f = 0; f < 16; ++f) {
        acc[f][0] *= corr; acc[f][1] *= corr;
        acc[f][2] *= corr; acc[f][3] *= corr;
      }
      l *= corr;
      m = mn;
    }
    float p[8];
    float psum = 0.f;
#pragma unroll
    for (int r = 0; r < 4; ++r) {
      p[r] = __expf(st0[r] * SCALE - m);
      p[4 + r] = __expf(st1[r] * SCALE - m);
      psum += p[r] + p[4 + r];
    }
    psum += __shfl_xor(psum, 16, 64);
    psum += __shfl_xor(psum, 32, 64);
    l += psum;
    // ---- write P^T (bf16) to per-wave LDS: plds[query][key] ----
    {
      uint2 pk0, pk1;
      pk0.x = bf16rne(p[0]) | (bf16rne(p[1]) << 16);
      pk0.y = bf16rne(p[2]) | (bf16rne(p[3]) << 16);
      pk1.x = bf16rne(p[4]) | (bf16rne(p[5]) << 16);
      pk1.y = bf16rne(p[6]) | (bf16rne(p[7]) << 16);
      *(uint2*)(plc + lrow * 80 + g * 8) = pk0;
      *(uint2*)(plc + lrow * 80 + 32 + g * 8) = pk1;
    }
    asm volatile("s_waitcnt lgkmcnt(0)" ::: "memory");
    // ---- O^T += V^T * P (16 MFMAs) ----
    bf16x8 pf = *(const bf16x8*)(plc + lrow * 80 + g * 16);
    __builtin_amdgcn_s_setprio(1);
#pragma unroll
    for (int f = 0; f < 16; ++f) {
      int dim = f * 16 + lrow;
      bf16x8 vf = *(const bf16x8*)(vtc + dim * 80 + g * 16);
      acc[f] = __builtin_amdgcn_mfma_f32_16x16x32_bf16(vf, pf, acc[f], 0, 0, 0);
    }
    __builtin_amdgcn_s_setprio(0);
  }
#undef LOADT
  // ---- epilogue: store unnormalized partial O as bf16 + (m,l) ----
  unsigned short* dstp = ogp + ((size_t)(split * 4 + bh) * LTOT + qi) * DH;
#pragma unroll
  for (int f = 0; f < 16; ++f) {
    uint2 pk;
    pk.x = bf16rne(acc[f][0]) | (bf16rne(acc[f][1]) << 16);
    pk.y = bf16rne(acc[f][2]) | (bf16rne(acc[f][3]) << 16);
    *(uint2*)(dstp + f * 16 + g * 4) = pk;
  }
  if (g == 0) ml[(size_t)(split * 4 + bh) * LTOT + qi] = make_float2(m, l);
}

// Combine splits + overlap-add gather + crop. Vectorized: lane = 4-dim group
// (uint2 loads), 4 waves split the covering windows, LDS reduction.
__global__ __launch_bounds__(256) void overlap_kernel(
    const unsigned short* __restrict__ ogp, const float2* __restrict__ ml,
    float* __restrict__ crop) {
  __shared__ float w0s[64], w1s[64];
  __shared__ float part[4 * 256];
  int r = blockIdx.x;  // 256 = B*h*64 pixels
  int tid = threadIdx.x;
  int w4 = tid >> 6;
  int dg = tid & 63;  // dim group: dims dg*4 .. dg*4+3
  int p = r & 63;
  int head = (r >> 6) & 1;
  int b = r >> 7;
  int bh = b * 2 + head;
  int y = p >> 3, x = p & 7;
  int py = y + TP, px = x + LP;
  int i0 = max(0, py - 7), i1 = min(7, py);
  int j0 = max(0, px - 7), j1 = min(7, px);
  int ni = i1 - i0 + 1, nj = j1 - j0 + 1, nq = ni * nj;
  if (tid < nq) {
    int iw = i0 + tid / nj, jw = j0 + tid % nj;
    int tok = (py - iw) * 8 + (px - jw);
    int q = (iw * 8 + jw) * 64 + tok;
    float2 a = ml[(size_t)bh * 4096 + q];
    float2 c = ml[(size_t)(4 + bh) * 4096 + q];
    float M = fmaxf(a.x, c.x);
    float e0 = __expf(a.x - M), e1 = __expf(c.x - M);
    float rr = 1.f / (a.y * e0 + c.y * e1);
    w0s[tid] = e0 * rr;
    w1s[tid] = e1 * rr;
  }
  __syncthreads();
  float a0 = 0.f, a1 = 0.f, a2 = 0.f, a3 = 0.f;
  for (int t = w4; t < nq; t += 4) {
    int iw = i0 + t / nj, jw = j0 + t % nj;
    int tok = (py - iw) * 8 + (px - jw);
    int q = (iw * 8 + jw) * 64 + tok;
    size_t e = ((size_t)bh * 4096 + q) * 256 + dg * 4;
    uint2 o0 = *(const uint2*)(ogp + e);
    uint2 o1 = *(const uint2*)(ogp + (size_t)4 * LTOT * DH + e);
    float cw0 = w0s[t], cw1 = w1s[t];
    a0 += cw0 * bf2f((unsigned short)(o0.x & 0xffff)) + cw1 * bf2f((unsigned short)(o1.x & 0xffff));
    a1 += cw0 * bf2f((unsigned short)(o0.x >> 16)) + cw1 * bf2f((unsigned short)(o1.x >> 16));
    a2 += cw0 * bf2f((unsigned short)(o0.y & 0xffff)) + cw1 * bf2f((unsigned short)(o1.y & 0xffff));
    a3 += cw0 * bf2f((unsigned short)(o0.y >> 16)) + cw1 * bf2f((unsigned short)(o1.y >> 16));
  }
  part[w4 * 256 + dg * 4 + 0] = a0;
  part[w4 * 256 + dg * 4 + 1] = a1;
  part[w4 * 256 + dg * 4 + 2] = a2;
  part[w4 * 256 + dg * 4 + 3] = a3;
  __syncthreads();
  float s = part[tid] + part[256 + tid] + part[512 + tid] + part[768 + tid];
  float cnt = (float)nq;
  crop[((size_t)b * CC + head * DH + tid) * 64 + p] = s / (cnt + 1e-6f);
}

// out = x_feat + a * (Wproj @ crop + bproj)
__global__ __launch_bounds__(256) void final_kernel(
    const float* __restrict__ crop, const float* __restrict__ Wp,
    const float* __restrict__ bp, const float* __restrict__ x_feat,
    const float* __restrict__ pa, float* __restrict__ out) {
  int blocksPerB = CC >> 2;
  int b = blockIdx.x / blocksPerB;
  int ob = blockIdx.x - b * blocksPerB;
  int o = ob * 4 + (threadIdx.x >> 6);
  int p = threadIdx.x & 63;
  float a = 2.f / (1.f + __expf(-pa[0]));
  const float* xb = crop + (size_t)b * CC * 64;
  const float* wr = Wp + (size_t)o * CC;
  float acc = 0.f;
#pragma unroll 8
  for (int c = 0; c < CC; ++c) acc += wr[c] * xb[c * 64 + p];
  size_t oi = ((size_t)b * CC + o) * 64 + p;
  out[oi] = x_feat[oi] + a * (acc + bp[o]);
}

extern "C" void kernel_launch(void* const* d_in, const int* in_sizes, int n_in,
                              void* d_out, int out_size, void* d_ws, size_t ws_size,
                              hipStream_t stream) {
  const float* x_feat = (const float*)d_in[0];
  const float* z_feat = (const float*)d_in[1];
  const float* Wqkv = (const float*)d_in[2];
  const float* bqkv = (const float*)d_in[3];
  const float* Wqkz = (const float*)d_in[4];
  const float* bqkz = (const float*)d_in[5];
  const float* Wproj = (const float*)d_in[6];
  const float* bproj = (const float*)d_in[7];
  const float* pa = (const float*)d_in[8];
  const float* pbeta = (const float*)d_in[9];
  float* ws = (float*)d_ws;
  float* qkvx = ws;                                        // 196608 f
  float* qkz = ws + 196608;                                // 131072 f
  unsigned short* qgb = (unsigned short*)(ws + 327680);    // 2097152 f
  unsigned short* qgT = (unsigned short*)(ws + 2424832);   // 2097152 f
  unsigned short* ogp = (unsigned short*)(ws + 4521984);   // 4194304 f (2 splits)
  float2* ml = (float2*)(ws + 8716288);                    // 65536 f
  float* crop = ws;                                        // alias qkvx (dead after local_attn)
  float* out = (float*)d_out;

  conv_both_kernel<<<BB * (1536 / 4) + BB * (1024 / 4), 256, 0, stream>>>(
      x_feat, Wqkv, bqkv, qkvx, z_feat, Wqkz, bqkz, qkz);
  local_attn_kernel<<<256, 256, 0, stream>>>(qkvx, qkz, pbeta, qgb, qgT);
  gattn_mfma<<<512, 256, 0, stream>>>(qgb, qgT, ogp, ml);
  overlap_kernel<<<256, 256, 0, stream>>>(ogp, ml, crop);
  final_kernel<<<BB * (CC / 4), 256, 0, stream>>>(crop, Wproj, bproj, x_feat, pa, out);
}